// Round 7
// baseline (296.580 us; speedup 1.0000x reference)
//
#include <hip/hip_runtime.h>
#include <math.h>

// Problem constants
#define NREL 499        // 2*MAX_LEN-1
#define NREL_PAD 500    // row stride for qrel (2000 B, 16-B aligned)
#define LDB 72          // bf16 LDS row stride (flash P buffer)
#define LDT 72          // bf16 LDS row stride (gemm tiles)

typedef __attribute__((ext_vector_type(8))) short bf16x8;
typedef __attribute__((ext_vector_type(4))) float f32x4;

__device__ __forceinline__ float bf2f(ushort x) {
  union { unsigned u; float f; } v; v.u = ((unsigned)x) << 16; return v.f;
}
__device__ __forceinline__ ushort f2bf(float x) {
  union { float f; unsigned u; } v; v.f = x;
  return (ushort)((v.u + 0x8000u) >> 16);
}
__device__ __forceinline__ bf16x8 pack8(float4 a, float4 b) {
  bf16x8 r;
  r[0] = (short)f2bf(a.x); r[1] = (short)f2bf(a.y);
  r[2] = (short)f2bf(a.z); r[3] = (short)f2bf(a.w);
  r[4] = (short)f2bf(b.x); r[5] = (short)f2bf(b.y);
  r[6] = (short)f2bf(b.z); r[7] = (short)f2bf(b.w);
  return r;
}

// ============================================================================
// prep_wt: Wt[z][n][k] (bf16) = W_z[k][n], z = {q,k,v,o}. Grid (8,8,4).
// Blocks (0,0,z) additionally build maskbf[b][j] = mask ? 1.0bf : 0.0bf.
// ============================================================================
__global__ __launch_bounds__(256) void prep_wt(const float* __restrict__ W0,
                                               const float* __restrict__ W1,
                                               const float* __restrict__ W2,
                                               const float* __restrict__ W3,
                                               const int* __restrict__ mask,
                                               ushort* __restrict__ Wt,
                                               ushort* __restrict__ maskbf) {
  __shared__ float T[64][68];
  const int t = threadIdx.x;
  const int k0 = blockIdx.x * 64, n0 = blockIdx.y * 64, z = blockIdx.z;
  const float* W = (z == 0) ? W0 : (z == 1) ? W1 : (z == 2) ? W2 : W3;
#pragma unroll
  for (int s = 0; s < 4; ++s) {
    int idx = t + s * 256;
    int r = idx >> 4, c4 = (idx & 15) << 2;
    *(float4*)&T[r][c4] = *(const float4*)(W + (size_t)(k0 + r) * 512 + n0 + c4);
  }
  if (blockIdx.x == 0 && blockIdx.y == 0) {
    int base = z * 1024 + t * 4;
    int4 mv = *(const int4*)(mask + base);
    ushort4 mo;
    mo.x = mv.x ? 0x3F80 : 0; mo.y = mv.y ? 0x3F80 : 0;
    mo.z = mv.z ? 0x3F80 : 0; mo.w = mv.w ? 0x3F80 : 0;
    *(ushort4*)(maskbf + base) = mo;
  }
  __syncthreads();
#pragma unroll
  for (int s = 0; s < 4; ++s) {
    int idx = t + s * 256;
    int row = idx >> 4, c4 = (idx & 15) << 2;  // row = n_local, c4 = k_local
    ushort4 u = make_ushort4(f2bf(T[c4 + 0][row]), f2bf(T[c4 + 1][row]),
                             f2bf(T[c4 + 2][row]), f2bf(T[c4 + 3][row]));
    *(ushort4*)(Wt + (size_t)z * 262144 + (size_t)(n0 + row) * 512 + k0 + c4) = u;
  }
}

// ============================================================================
// gemm_tile_body: C[64x64 tile] = A @ Wt^T(bf16 [n][k]) + bias.
// AFP32=1: A is fp32 and is cast to bf16 during LDS staging (fused cast).
// AFP32=0: A already bf16.
// MODE 0: fp32 row-major out [4096][512]               (output projection)
// MODE 1: bf16 Vt [bh][64 d][2048 l], masked columns zeroed (mvec)
// MODE 2: bf16 row-major head-split [bh][2048 l][64 d], scaled by oscale
// ============================================================================
template <int MODE, int AFP32>
__device__ __forceinline__ void gemm_tile_body(const void* __restrict__ Av,
                                               const ushort* __restrict__ Wt,
                                               const float* __restrict__ bias,
                                               const int* __restrict__ mvec,
                                               void* __restrict__ outv,
                                               int bx, int by, float oscale) {
  __shared__ ushort As[64 * LDT];
  __shared__ ushort Bs[64 * LDT];
  const int t = threadIdx.x;
  const int lane = t & 63, wave = t >> 6;
  const int m16 = lane & 15, quad = lane >> 4;
  const int koff = quad << 3;
  const int i0 = by * 64, n0 = bx * 64;
  const int row0 = t >> 3, off0 = (t & 7) << 3;
  const int row1 = (t + 256) >> 3, off1 = ((t + 256) & 7) << 3;
  const ushort* Ab16 = (const ushort*)Av + (size_t)i0 * 512;
  const float*  Ab32 = (const float*)Av + (size_t)i0 * 512;
  const ushort* Bb = Wt + (size_t)n0 * 512;

  uint4 ar0, ar1;
  float4 af00, af01, af10, af11;
  if (AFP32) {
    af00 = *(const float4*)(Ab32 + (size_t)row0 * 512 + off0);
    af01 = *(const float4*)(Ab32 + (size_t)row0 * 512 + off0 + 4);
    af10 = *(const float4*)(Ab32 + (size_t)row1 * 512 + off1);
    af11 = *(const float4*)(Ab32 + (size_t)row1 * 512 + off1 + 4);
  } else {
    ar0 = *(const uint4*)(Ab16 + (size_t)row0 * 512 + off0);
    ar1 = *(const uint4*)(Ab16 + (size_t)row1 * 512 + off1);
  }
  uint4 br0 = *(const uint4*)(Bb + (size_t)row0 * 512 + off0);
  uint4 br1 = *(const uint4*)(Bb + (size_t)row1 * 512 + off1);

  f32x4 acc[4] = {{0.f, 0.f, 0.f, 0.f}, {0.f, 0.f, 0.f, 0.f},
                  {0.f, 0.f, 0.f, 0.f}, {0.f, 0.f, 0.f, 0.f}};

  for (int ks = 0; ks < 8; ++ks) {
    __syncthreads();
    if (AFP32) {
      *(bf16x8*)&As[row0 * LDT + off0] = pack8(af00, af01);
      *(bf16x8*)&As[row1 * LDT + off1] = pack8(af10, af11);
    } else {
      *(uint4*)&As[row0 * LDT + off0] = ar0;
      *(uint4*)&As[row1 * LDT + off1] = ar1;
    }
    *(uint4*)&Bs[row0 * LDT + off0] = br0;
    *(uint4*)&Bs[row1 * LDT + off1] = br1;
    __syncthreads();

    const int kn = ((ks + 1) & 7) << 6;
    if (AFP32) {
      af00 = *(const float4*)(Ab32 + (size_t)row0 * 512 + kn + off0);
      af01 = *(const float4*)(Ab32 + (size_t)row0 * 512 + kn + off0 + 4);
      af10 = *(const float4*)(Ab32 + (size_t)row1 * 512 + kn + off1);
      af11 = *(const float4*)(Ab32 + (size_t)row1 * 512 + kn + off1 + 4);
    } else {
      ar0 = *(const uint4*)(Ab16 + (size_t)row0 * 512 + kn + off0);
      ar1 = *(const uint4*)(Ab16 + (size_t)row1 * 512 + kn + off1);
    }
    br0 = *(const uint4*)(Bb + (size_t)row0 * 512 + kn + off0);
    br1 = *(const uint4*)(Bb + (size_t)row1 * 512 + kn + off1);

    __builtin_amdgcn_s_setprio(1);
    if (MODE != 1) {
#pragma unroll
      for (int kh = 0; kh < 2; ++kh) {
        bf16x8 af = *(const bf16x8*)&As[((wave << 4) + m16) * LDT + (kh << 5) + koff];
#pragma unroll
        for (int nt = 0; nt < 4; ++nt) {
          bf16x8 wf = *(const bf16x8*)&Bs[((nt << 4) + m16) * LDT + (kh << 5) + koff];
          acc[nt] = __builtin_amdgcn_mfma_f32_16x16x32_bf16(af, wf, acc[nt], 0, 0, 0);
        }
      }
    } else {
#pragma unroll
      for (int kh = 0; kh < 2; ++kh) {
        bf16x8 wf = *(const bf16x8*)&Bs[((wave << 4) + m16) * LDT + (kh << 5) + koff];
#pragma unroll
        for (int it = 0; it < 4; ++it) {
          bf16x8 af = *(const bf16x8*)&As[((it << 4) + m16) * LDT + (kh << 5) + koff];
          acc[it] = __builtin_amdgcn_mfma_f32_16x16x32_bf16(wf, af, acc[it], 0, 0, 0);
        }
      }
    }
    __builtin_amdgcn_s_setprio(0);
  }

  if (MODE == 0) {
    float* out = (float*)outv;
#pragma unroll
    for (int nt = 0; nt < 4; ++nt) {
      float bn = bias[n0 + (nt << 4) + m16];
#pragma unroll
      for (int r = 0; r < 4; ++r) {
        int i = i0 + (wave << 4) + (quad << 2) + r;
        out[(size_t)i * 512 + n0 + (nt << 4) + m16] = acc[nt][r] + bn;
      }
    }
  } else if (MODE == 2) {
    ushort* out = (ushort*)outv;
    const int b = i0 >> 11, l0 = i0 & 2047, h = n0 >> 6;
#pragma unroll
    for (int nt = 0; nt < 4; ++nt) {
      float bn = bias[n0 + (nt << 4) + m16];
      int d = (nt << 4) + m16;
#pragma unroll
      for (int r = 0; r < 4; ++r) {
        int il = (wave << 4) + (quad << 2) + r;
        out[((size_t)(b * 8 + h) * 2048 + l0 + il) * 64 + d] =
            f2bf((acc[nt][r] + bn) * oscale);
      }
    }
  } else {  // MODE 1: Vt [bh][d][l], masked columns -> 0
    ushort* out = (ushort*)outv;
    const int b = i0 >> 11, l0 = i0 & 2047, h = n0 >> 6;
    float4 b4 = *(const float4*)(bias + n0 + (wave << 4) + (quad << 2));
    float bb[4] = {b4.x, b4.y, b4.z, b4.w};
    float mkf[4];
#pragma unroll
    for (int it = 0; it < 4; ++it)
      mkf[it] = (mvec[b * 2048 + l0 + (it << 4) + m16] != 0) ? 1.f : 0.f;
#pragma unroll
    for (int r = 0; r < 4; ++r) {
      int d = (wave << 4) + (quad << 2) + r;
#pragma unroll
      for (int it = 0; it < 4; ++it) {
        out[((size_t)(b * 8 + h) * 64 + d) * 2048 + l0 + (it << 4) + m16] =
            f2bf((acc[it][r] + bb[r]) * mkf[it]);
      }
    }
  }
}

template <int MODE, int AFP32>
__global__ __launch_bounds__(256) void gemm_tile(const void* __restrict__ A,
                                                 const ushort* __restrict__ Wt,
                                                 const float* __restrict__ bias,
                                                 void* __restrict__ outv) {
  gemm_tile_body<MODE, AFP32>(A, Wt, bias, nullptr, outv, blockIdx.x,
                              blockIdx.y, 1.f);
}

// Merged QKV projection with fused fp32->bf16 A staging. Grid (8, 64, 3).
// Q output pre-scaled by 0.125 (exact in bf16); rel pre-scaled by 8 in
// qrel_mfma so qrel values are bitwise unchanged.
__global__ __launch_bounds__(256) void gemm_qkv(
    const float* __restrict__ q, const float* __restrict__ k,
    const float* __restrict__ v, const ushort* __restrict__ Wt,
    const float* __restrict__ bq, const float* __restrict__ bk,
    const float* __restrict__ bv, const int* __restrict__ mask,
    ushort* __restrict__ Qw, ushort* __restrict__ Kw, ushort* __restrict__ Vtw) {
  const int z = blockIdx.z;
  if (z == 0) {
    gemm_tile_body<2, 1>(q, Wt, bq, nullptr, (void*)Qw, blockIdx.x, blockIdx.y,
                         0.125f);
  } else if (z == 1) {
    gemm_tile_body<2, 1>(k, Wt + 262144, bk, nullptr, (void*)Kw, blockIdx.x,
                         blockIdx.y, 1.f);
  } else {
    gemm_tile_body<1, 1>(v, Wt + 2 * 262144, bv, mask, (void*)Vtw, blockIdx.x,
                         blockIdx.y, 1.f);
  }
}

// ============================================================================
// qrel_mfma: qrel[bh][i][r] = sum_d Q[bh][i][d]*rel[r][d] (fp32, stride
// NREL_PAD). Q is pre-scaled by 1/8, rel scaled here by 8 -> identical values.
// ============================================================================
__global__ __launch_bounds__(256) void qrel_mfma(const ushort* __restrict__ Qw,
                                                 const float* __restrict__ rel,
                                                 float* __restrict__ qrel) {
  const int t = threadIdx.x;
  const int lane = t & 63, wave = t >> 6;
  const int m16 = lane & 15, quad = lane >> 4;
  const int r0 = blockIdx.x * 64;
  const int i0 = blockIdx.y * 64;
  const int bh = blockIdx.z;
  const ushort* Qb = Qw + ((size_t)bh * 2048 + i0 + (wave << 4) + m16) * 64;
  bf16x8 qa0 = *(const bf16x8*)(Qb + (quad << 3));
  bf16x8 qa1 = *(const bf16x8*)(Qb + 32 + (quad << 3));

  f32x4 acc[4] = {{0.f, 0.f, 0.f, 0.f}, {0.f, 0.f, 0.f, 0.f},
                  {0.f, 0.f, 0.f, 0.f}, {0.f, 0.f, 0.f, 0.f}};
#pragma unroll
  for (int rt = 0; rt < 4; ++rt) {
    int rr = min(r0 + (rt << 4) + m16, NREL - 1);
    const float* rp = rel + (size_t)rr * 64 + (quad << 3);
    float4 a0 = *(const float4*)rp,        a1 = *(const float4*)(rp + 4);
    float4 a2 = *(const float4*)(rp + 32), a3 = *(const float4*)(rp + 36);
    a0.x *= 8.f; a0.y *= 8.f; a0.z *= 8.f; a0.w *= 8.f;
    a1.x *= 8.f; a1.y *= 8.f; a1.z *= 8.f; a1.w *= 8.f;
    a2.x *= 8.f; a2.y *= 8.f; a2.z *= 8.f; a2.w *= 8.f;
    a3.x *= 8.f; a3.y *= 8.f; a3.z *= 8.f; a3.w *= 8.f;
    bf16x8 rf0 = pack8(a0, a1);
    bf16x8 rf1 = pack8(a2, a3);
    acc[rt] = __builtin_amdgcn_mfma_f32_16x16x32_bf16(qa0, rf0, acc[rt], 0, 0, 0);
    acc[rt] = __builtin_amdgcn_mfma_f32_16x16x32_bf16(qa1, rf1, acc[rt], 0, 0, 0);
  }
#pragma unroll
  for (int rt = 0; rt < 4; ++rt) {
    int r = r0 + (rt << 4) + m16;
    if (r < NREL_PAD) {
#pragma unroll
      for (int rg = 0; rg < 4; ++rg) {
        int i = i0 + (wave << 4) + (quad << 2) + rg;
        qrel[((size_t)bh * 2048 + i) * NREL_PAD + r] = acc[rt][rg];
      }
    }
  }
}

// ============================================================================
// qrel gather for one 64-j tile; wave-uniform clamp shortcut with the two
// edge values hoisted (zero loads on fully-clamped tiles).
// ============================================================================
__device__ __forceinline__ void gather_qv(float qv[4][4],
                                          const float* __restrict__ qrow,
                                          float e_lo, float e_hi,
                                          int iq, int iw0, int j0, int quad) {
  if (j0 - iw0 >= 264) {  // j - i >= 249 for all pairs -> rr = 498
#pragma unroll
    for (int jt = 0; jt < 4; ++jt)
#pragma unroll
      for (int r = 0; r < 4; ++r) qv[jt][r] = e_hi;
  } else if (iw0 - j0 >= 312) {  // i - j >= 249 for all pairs -> rr = 0
#pragma unroll
    for (int jt = 0; jt < 4; ++jt)
#pragma unroll
      for (int r = 0; r < 4; ++r) qv[jt][r] = e_lo;
  } else {
#pragma unroll
    for (int jt = 0; jt < 4; ++jt) {
#pragma unroll
      for (int r = 0; r < 4; ++r) {
        int j = j0 + (jt << 4) + (quad << 2) + r;
        int rr = min(NREL - 1, max(0, j - iq + 249));
        qv[jt][r] = qrow[rr];
      }
    }
  }
}

// ============================================================================
// Flash attention, barrier-free: K/V/Q fragments read DIRECTLY from global
// (L2-resident; swapped-operand layout makes every lane's fragment a
// contiguous 16-B load). LDS holds only P (per-wave region). No
// __syncthreads in the main loop — waves pipeline independently.
//  - K frags prefetched 1 iter ahead (full-iter slack);
//  - V frags issued at iter top, consumed after softmax (~L2 latency hidden);
//  - defer-max (THR=8); XCD-aware block swizzle.
// ============================================================================
__global__ __launch_bounds__(256, 2) void flash_attn(
    const ushort* __restrict__ Qw, const ushort* __restrict__ Kw,
    const ushort* __restrict__ Vt, const float* __restrict__ qrel,
    const ushort* __restrict__ maskbf, ushort* __restrict__ attnbf) {
  __shared__ ushort Ps[64 * LDB];  // P tile only (per-wave 16-row regions)
  const int t = threadIdx.x;
  const int lane = t & 63, wave = t >> 6;
  const int m16 = lane & 15, quad = lane >> 4;
  const int koff = quad << 3;
  const int bid = ((int)blockIdx.y << 5) + (int)blockIdx.x;
  const int swz = ((bid & 7) << 6) + (bid >> 3);  // XCD-contiguous chunks
  const int i0 = (swz & 31) << 6;
  const int bh = swz >> 5;
  const int b = bh >> 3, h = bh & 7;
  const ushort* Kb = Kw + (size_t)bh * 2048 * 64;
  const ushort* Vb = Vt + (size_t)bh * 64 * 2048;
  const ushort* mbf = maskbf + b * 2048;
  const int iw0 = i0 + (wave << 4);
  const int iq = iw0 + m16;  // this lane's output row
  const float* qrow = qrel + ((size_t)bh * 2048 + iq) * NREL_PAD;
  const float e_lo = qrow[0], e_hi = qrow[NREL - 1];

  // Q fragments direct from global (once)
  const ushort* qp = Qw + ((size_t)bh * 2048 + iq) * 64 + koff;
  bf16x8 qa0 = *(const bf16x8*)qp;
  bf16x8 qa1 = *(const bf16x8*)(qp + 32);

  // prologue: prefetch K fragments for j0 = 0
  bf16x8 kf[8];
#pragma unroll
  for (int jt = 0; jt < 4; ++jt) {
    const ushort* kp = Kb + (size_t)((jt << 4) + m16) * 64 + koff;
    kf[jt * 2]     = *(const bf16x8*)kp;
    kf[jt * 2 + 1] = *(const bf16x8*)(kp + 32);
  }

  float m_i = -INFINITY;
  f32x4 oacc[4];
  f32x4 lacc = {0.f, 0.f, 0.f, 0.f};
#pragma unroll
  for (int dt = 0; dt < 4; ++dt) oacc[dt] = (f32x4){0.f, 0.f, 0.f, 0.f};
  const int prow = ((wave << 4) + m16) * LDB;

  for (int j0 = 0; j0 < 2048; j0 += 64) {
    // ---- issue current-tile V / mask / qrel loads (consumed late) ----
    bf16x8 vf[8];
#pragma unroll
    for (int dt = 0; dt < 4; ++dt) {
      const ushort* vp = Vb + (size_t)((dt << 4) + m16) * 2048 + j0 + koff;
      vf[dt * 2]     = *(const bf16x8*)vp;
      vf[dt * 2 + 1] = *(const bf16x8*)(vp + 32);
    }
    bf16x8 mf0 = *(const bf16x8*)(mbf + j0 + koff);
    bf16x8 mf1 = *(const bf16x8*)(mbf + j0 + 32 + koff);
    float qv[4][4];
    gather_qv(qv, qrow, e_lo, e_hi, iq, iw0, j0, quad);

    // ---- QK^T on prefetched K fragments ----
    f32x4 sacc[4];
    __builtin_amdgcn_s_setprio(1);
#pragma unroll
    for (int jt = 0; jt < 4; ++jt) {
      f32x4 z = {0.f, 0.f, 0.f, 0.f};
      z = __builtin_amdgcn_mfma_f32_16x16x32_bf16(kf[jt * 2], qa0, z, 0, 0, 0);
      z = __builtin_amdgcn_mfma_f32_16x16x32_bf16(kf[jt * 2 + 1], qa1, z, 0, 0, 0);
      sacc[jt] = z;
    }
    __builtin_amdgcn_s_setprio(0);

    // ---- prefetch K fragments for next tile (full-iter slack) ----
    const int jn = (j0 + 64) & 2047;  // wraps on last iter (unused)
#pragma unroll
    for (int jt = 0; jt < 4; ++jt) {
      const ushort* kp = Kb + (size_t)(jn + (jt << 4) + m16) * 64 + koff;
      kf[jt * 2]     = *(const bf16x8*)kp;
      kf[jt * 2 + 1] = *(const bf16x8*)(kp + 32);
    }

    // ---- bias add + row max (in-register + 2 cross-quad shfl) ----
#pragma unroll
    for (int jt = 0; jt < 4; ++jt)
#pragma unroll
      for (int r = 0; r < 4; ++r) sacc[jt][r] += qv[jt][r];

    float t0 = fmaxf(fmaxf(sacc[0][0], sacc[0][1]), fmaxf(sacc[0][2], sacc[0][3]));
    float t1 = fmaxf(fmaxf(sacc[1][0], sacc[1][1]), fmaxf(sacc[1][2], sacc[1][3]));
    float t2 = fmaxf(fmaxf(sacc[2][0], sacc[2][1]), fmaxf(sacc[2][2], sacc[2][3]));
    float t3 = fmaxf(fmaxf(sacc[3][0], sacc[3][1]), fmaxf(sacc[3][2], sacc[3][3]));
    float mx = fmaxf(fmaxf(t0, t1), fmaxf(t2, t3));
    mx = fmaxf(mx, __shfl_xor(mx, 16));
    mx = fmaxf(mx, __shfl_xor(mx, 32));

    // ---- defer-max: rescale only on real growth (P bounded by e^8) ----
    if (__any(mx > m_i + 8.f)) {
      float mnew = fmaxf(m_i, mx);
      float al = __expf(m_i - mnew);
      m_i = mnew;
#pragma unroll
      for (int dt = 0; dt < 4; ++dt)
#pragma unroll
        for (int r = 0; r < 4; ++r) oacc[dt][r] *= al;
#pragma unroll
      for (int r = 0; r < 4; ++r) lacc[r] *= al;
    }

    // ---- P = exp(S - m_i) -> LDS (per-wave region, b64 runs) ----
#pragma unroll
    for (int jt = 0; jt < 4; ++jt) {
      ushort4 pk;
      pk.x = f2bf(__expf(sacc[jt][0] - m_i));
      pk.y = f2bf(__expf(sacc[jt][1] - m_i));
      pk.z = f2bf(__expf(sacc[jt][2] - m_i));
      pk.w = f2bf(__expf(sacc[jt][3] - m_i));
      *(ushort4*)&Ps[prow + (jt << 4) + (quad << 2)] = pk;
    }
    __asm__ volatile("s_waitcnt lgkmcnt(0)" ::: "memory");

    bf16x8 pa0 = *(const bf16x8*)&Ps[prow + koff];
    bf16x8 pa1 = *(const bf16x8*)&Ps[prow + 32 + koff];
    __builtin_amdgcn_s_setprio(1);
    lacc = __builtin_amdgcn_mfma_f32_16x16x32_bf16(mf0, pa0, lacc, 0, 0, 0);
    lacc = __builtin_amdgcn_mfma_f32_16x16x32_bf16(mf1, pa1, lacc, 0, 0, 0);
#pragma unroll
    for (int dt = 0; dt < 4; ++dt) {
      oacc[dt] = __builtin_amdgcn_mfma_f32_16x16x32_bf16(vf[dt * 2], pa0, oacc[dt], 0, 0, 0);
      oacc[dt] = __builtin_amdgcn_mfma_f32_16x16x32_bf16(vf[dt * 2 + 1], pa1, oacc[dt], 0, 0, 0);
    }
    __builtin_amdgcn_s_setprio(0);
  }

  // epilogue: lane holds O[iq][d = dt*16 + quad*4 + r]; l = lacc[0]
  float inv = 1.0f / lacc[0];
  ushort* dst = attnbf + (size_t)(b * 2048 + iq) * 512 + h * 64;
#pragma unroll
  for (int dt = 0; dt < 4; ++dt) {
    ushort4 st;
    st.x = f2bf(oacc[dt][0] * inv);
    st.y = f2bf(oacc[dt][1] * inv);
    st.z = f2bf(oacc[dt][2] * inv);
    st.w = f2bf(oacc[dt][3] * inv);
    *(ushort4*)(dst + (dt << 4) + (quad << 2)) = st;
  }
}

// ============================================================================
extern "C" void kernel_launch(void* const* d_in, const int* in_sizes, int n_in,
                              void* d_out, int out_size, void* d_ws,
                              size_t ws_size, hipStream_t stream) {
  const float* query = (const float*)d_in[0];
  const float* key   = (const float*)d_in[1];
  const float* value = (const float*)d_in[2];
  const int*   mask  = (const int*)d_in[3];
  const float* Wq = (const float*)d_in[4];
  const float* bq = (const float*)d_in[5];
  const float* Wk = (const float*)d_in[6];
  const float* bk = (const float*)d_in[7];
  const float* Wv = (const float*)d_in[8];
  const float* bv = (const float*)d_in[9];
  const float* Wo = (const float*)d_in[10];
  const float* bo = (const float*)d_in[11];
  const float* rel = (const float*)d_in[12];

  char* w = (char*)d_ws;
  size_t off = 0;
  ushort* Qw  = (ushort*)(w + off); off += (size_t)16 * 2048 * 64 * 2;       // 4 MB
  ushort* Kw  = (ushort*)(w + off); off += (size_t)16 * 2048 * 64 * 2;       // 4 MB
  ushort* Vtw = (ushort*)(w + off); off += (size_t)16 * 64 * 2048 * 2;       // 4 MB
  ushort* Wt  = (ushort*)(w + off); off += (size_t)4 * 512 * 512 * 2;        // 2 MB
  float* qrel = (float*)(w + off);  off += (size_t)16 * 2048 * NREL_PAD * 4; // 65.5 MB
  ushort* attnbf = (ushort*)(w + off); off += (size_t)4096 * 512 * 2;        // 4 MB
  ushort* maskbf = (ushort*)(w + off); off += (size_t)2 * 2048 * 2;          // 8 KB
  float* out = (float*)d_out;

  dim3 bb(256);
  hipLaunchKernelGGL(prep_wt, dim3(8, 8, 4), bb, 0, stream, Wq, Wk, Wv, Wo,
                     mask, Wt, maskbf);
  hipLaunchKernelGGL(gemm_qkv, dim3(8, 64, 3), bb, 0, stream, query, key, value,
                     Wt, bq, bk, bv, mask, Qw, Kw, Vtw);
  hipLaunchKernelGGL(qrel_mfma, dim3(8, 32, 16), bb, 0, stream, Qw, rel, qrel);
  hipLaunchKernelGGL(flash_attn, dim3(32, 16), bb, 0, stream, Qw, Kw, Vtw, qrel,
                     maskbf, attnbf);
  hipLaunchKernelGGL((gemm_tile<0, 0>), dim3(8, 64), bb, 0, stream, attnbf,
                     Wt + 3 * 262144, bo, (void*)out);
}

// Round 8
// 242.606 us; speedup vs baseline: 1.2225x; 1.2225x over previous
//
#include <hip/hip_runtime.h>
#include <math.h>

// Problem constants
#define NREL 499        // 2*MAX_LEN-1
#define NREL_PAD 500    // row stride for qrel (2000 B, 16-B aligned)
#define LDB 72          // bf16 LDS row stride (flash kernel)
#define LDT 72          // bf16 LDS row stride (gemm tiles)

typedef __attribute__((ext_vector_type(8))) short bf16x8;
typedef __attribute__((ext_vector_type(4))) float f32x4;

__device__ __forceinline__ float bf2f(ushort x) {
  union { unsigned u; float f; } v; v.u = ((unsigned)x) << 16; return v.f;
}
__device__ __forceinline__ ushort f2bf(float x) {
  union { float f; unsigned u; } v; v.f = x;
  return (ushort)((v.u + 0x8000u) >> 16);
}
__device__ __forceinline__ bf16x8 pack8(float4 a, float4 b) {
  bf16x8 r;
  r[0] = (short)f2bf(a.x); r[1] = (short)f2bf(a.y);
  r[2] = (short)f2bf(a.z); r[3] = (short)f2bf(a.w);
  r[4] = (short)f2bf(b.x); r[5] = (short)f2bf(b.y);
  r[6] = (short)f2bf(b.z); r[7] = (short)f2bf(b.w);
  return r;
}

// ============================================================================
// prep_wt: Wt[z][n][k] (bf16) = W_z[k][n], z = {q,k,v,o}. Grid (8,8,4).
// Blocks (0,0,z) additionally build maskbf[b][j] = mask ? 1.0bf : 0.0bf.
// ============================================================================
__global__ __launch_bounds__(256) void prep_wt(const float* __restrict__ W0,
                                               const float* __restrict__ W1,
                                               const float* __restrict__ W2,
                                               const float* __restrict__ W3,
                                               const int* __restrict__ mask,
                                               ushort* __restrict__ Wt,
                                               ushort* __restrict__ maskbf) {
  __shared__ float T[64][68];
  const int t = threadIdx.x;
  const int k0 = blockIdx.x * 64, n0 = blockIdx.y * 64, z = blockIdx.z;
  const float* W = (z == 0) ? W0 : (z == 1) ? W1 : (z == 2) ? W2 : W3;
#pragma unroll
  for (int s = 0; s < 4; ++s) {
    int idx = t + s * 256;
    int r = idx >> 4, c4 = (idx & 15) << 2;
    *(float4*)&T[r][c4] = *(const float4*)(W + (size_t)(k0 + r) * 512 + n0 + c4);
  }
  if (blockIdx.x == 0 && blockIdx.y == 0) {
    int base = z * 1024 + t * 4;
    int4 mv = *(const int4*)(mask + base);
    ushort4 mo;
    mo.x = mv.x ? 0x3F80 : 0; mo.y = mv.y ? 0x3F80 : 0;
    mo.z = mv.z ? 0x3F80 : 0; mo.w = mv.w ? 0x3F80 : 0;
    *(ushort4*)(maskbf + base) = mo;
  }
  __syncthreads();
#pragma unroll
  for (int s = 0; s < 4; ++s) {
    int idx = t + s * 256;
    int row = idx >> 4, c4 = (idx & 15) << 2;  // row = n_local, c4 = k_local
    ushort4 u = make_ushort4(f2bf(T[c4 + 0][row]), f2bf(T[c4 + 1][row]),
                             f2bf(T[c4 + 2][row]), f2bf(T[c4 + 3][row]));
    *(ushort4*)(Wt + (size_t)z * 262144 + (size_t)(n0 + row) * 512 + k0 + c4) = u;
  }
}

// ============================================================================
// gemm_tile_body: C[64x64 tile] = A @ Wt^T(bf16 [n][k]) + bias.
// AFP32=1: A fp32, cast to bf16 during LDS staging (fused cast).
// MODE 0: fp32 row-major out [4096][512]               (output projection)
// MODE 1: bf16 Vt [bh][64 d][2048 l], masked columns zeroed (mvec)
// MODE 2: bf16 row-major head-split [bh][2048 l][64 d], scaled by oscale
// ============================================================================
template <int MODE, int AFP32>
__device__ __forceinline__ void gemm_tile_body(const void* __restrict__ Av,
                                               const ushort* __restrict__ Wt,
                                               const float* __restrict__ bias,
                                               const int* __restrict__ mvec,
                                               void* __restrict__ outv,
                                               int bx, int by, float oscale) {
  __shared__ ushort As[64 * LDT];
  __shared__ ushort Bs[64 * LDT];
  const int t = threadIdx.x;
  const int lane = t & 63, wave = t >> 6;
  const int m16 = lane & 15, quad = lane >> 4;
  const int koff = quad << 3;
  const int i0 = by * 64, n0 = bx * 64;
  const int row0 = t >> 3, off0 = (t & 7) << 3;
  const int row1 = (t + 256) >> 3, off1 = ((t + 256) & 7) << 3;
  const ushort* Ab16 = (const ushort*)Av + (size_t)i0 * 512;
  const float*  Ab32 = (const float*)Av + (size_t)i0 * 512;
  const ushort* Bb = Wt + (size_t)n0 * 512;

  uint4 ar0, ar1;
  float4 af00, af01, af10, af11;
  if (AFP32) {
    af00 = *(const float4*)(Ab32 + (size_t)row0 * 512 + off0);
    af01 = *(const float4*)(Ab32 + (size_t)row0 * 512 + off0 + 4);
    af10 = *(const float4*)(Ab32 + (size_t)row1 * 512 + off1);
    af11 = *(const float4*)(Ab32 + (size_t)row1 * 512 + off1 + 4);
  } else {
    ar0 = *(const uint4*)(Ab16 + (size_t)row0 * 512 + off0);
    ar1 = *(const uint4*)(Ab16 + (size_t)row1 * 512 + off1);
  }
  uint4 br0 = *(const uint4*)(Bb + (size_t)row0 * 512 + off0);
  uint4 br1 = *(const uint4*)(Bb + (size_t)row1 * 512 + off1);

  f32x4 acc[4] = {{0.f, 0.f, 0.f, 0.f}, {0.f, 0.f, 0.f, 0.f},
                  {0.f, 0.f, 0.f, 0.f}, {0.f, 0.f, 0.f, 0.f}};

  for (int ks = 0; ks < 8; ++ks) {
    __syncthreads();
    if (AFP32) {
      *(bf16x8*)&As[row0 * LDT + off0] = pack8(af00, af01);
      *(bf16x8*)&As[row1 * LDT + off1] = pack8(af10, af11);
    } else {
      *(uint4*)&As[row0 * LDT + off0] = ar0;
      *(uint4*)&As[row1 * LDT + off1] = ar1;
    }
    *(uint4*)&Bs[row0 * LDT + off0] = br0;
    *(uint4*)&Bs[row1 * LDT + off1] = br1;
    __syncthreads();

    const int kn = ((ks + 1) & 7) << 6;
    if (AFP32) {
      af00 = *(const float4*)(Ab32 + (size_t)row0 * 512 + kn + off0);
      af01 = *(const float4*)(Ab32 + (size_t)row0 * 512 + kn + off0 + 4);
      af10 = *(const float4*)(Ab32 + (size_t)row1 * 512 + kn + off1);
      af11 = *(const float4*)(Ab32 + (size_t)row1 * 512 + kn + off1 + 4);
    } else {
      ar0 = *(const uint4*)(Ab16 + (size_t)row0 * 512 + kn + off0);
      ar1 = *(const uint4*)(Ab16 + (size_t)row1 * 512 + kn + off1);
    }
    br0 = *(const uint4*)(Bb + (size_t)row0 * 512 + kn + off0);
    br1 = *(const uint4*)(Bb + (size_t)row1 * 512 + kn + off1);

    __builtin_amdgcn_s_setprio(1);
    if (MODE != 1) {
#pragma unroll
      for (int kh = 0; kh < 2; ++kh) {
        bf16x8 af = *(const bf16x8*)&As[((wave << 4) + m16) * LDT + (kh << 5) + koff];
#pragma unroll
        for (int nt = 0; nt < 4; ++nt) {
          bf16x8 wf = *(const bf16x8*)&Bs[((nt << 4) + m16) * LDT + (kh << 5) + koff];
          acc[nt] = __builtin_amdgcn_mfma_f32_16x16x32_bf16(af, wf, acc[nt], 0, 0, 0);
        }
      }
    } else {
#pragma unroll
      for (int kh = 0; kh < 2; ++kh) {
        bf16x8 wf = *(const bf16x8*)&Bs[((wave << 4) + m16) * LDT + (kh << 5) + koff];
#pragma unroll
        for (int it = 0; it < 4; ++it) {
          bf16x8 af = *(const bf16x8*)&As[((it << 4) + m16) * LDT + (kh << 5) + koff];
          acc[it] = __builtin_amdgcn_mfma_f32_16x16x32_bf16(wf, af, acc[it], 0, 0, 0);
        }
      }
    }
    __builtin_amdgcn_s_setprio(0);
  }

  if (MODE == 0) {
    float* out = (float*)outv;
#pragma unroll
    for (int nt = 0; nt < 4; ++nt) {
      float bn = bias[n0 + (nt << 4) + m16];
#pragma unroll
      for (int r = 0; r < 4; ++r) {
        int i = i0 + (wave << 4) + (quad << 2) + r;
        out[(size_t)i * 512 + n0 + (nt << 4) + m16] = acc[nt][r] + bn;
      }
    }
  } else if (MODE == 2) {
    ushort* out = (ushort*)outv;
    const int b = i0 >> 11, l0 = i0 & 2047, h = n0 >> 6;
#pragma unroll
    for (int nt = 0; nt < 4; ++nt) {
      float bn = bias[n0 + (nt << 4) + m16];
      int d = (nt << 4) + m16;
#pragma unroll
      for (int r = 0; r < 4; ++r) {
        int il = (wave << 4) + (quad << 2) + r;
        out[((size_t)(b * 8 + h) * 2048 + l0 + il) * 64 + d] =
            f2bf((acc[nt][r] + bn) * oscale);
      }
    }
  } else {  // MODE 1: Vt [bh][d][l], masked columns -> 0
    ushort* out = (ushort*)outv;
    const int b = i0 >> 11, l0 = i0 & 2047, h = n0 >> 6;
    float4 b4 = *(const float4*)(bias + n0 + (wave << 4) + (quad << 2));
    float bb[4] = {b4.x, b4.y, b4.z, b4.w};
    float mkf[4];
#pragma unroll
    for (int it = 0; it < 4; ++it)
      mkf[it] = (mvec[b * 2048 + l0 + (it << 4) + m16] != 0) ? 1.f : 0.f;
#pragma unroll
    for (int r = 0; r < 4; ++r) {
      int d = (wave << 4) + (quad << 2) + r;
#pragma unroll
      for (int it = 0; it < 4; ++it) {
        out[((size_t)(b * 8 + h) * 64 + d) * 2048 + l0 + (it << 4) + m16] =
            f2bf((acc[it][r] + bb[r]) * mkf[it]);
      }
    }
  }
}

template <int MODE, int AFP32>
__global__ __launch_bounds__(256) void gemm_tile(const void* __restrict__ A,
                                                 const ushort* __restrict__ Wt,
                                                 const float* __restrict__ bias,
                                                 void* __restrict__ outv) {
  gemm_tile_body<MODE, AFP32>(A, Wt, bias, nullptr, outv, blockIdx.x,
                              blockIdx.y, 1.f);
}

// Merged QKV projection with fused fp32->bf16 A staging. Grid (8, 64, 3).
// Q output pre-scaled by 0.125 (exact in bf16); rel pre-scaled by 8 in
// qrel_mfma so qrel values are bitwise unchanged.
__global__ __launch_bounds__(256) void gemm_qkv(
    const float* __restrict__ q, const float* __restrict__ k,
    const float* __restrict__ v, const ushort* __restrict__ Wt,
    const float* __restrict__ bq, const float* __restrict__ bk,
    const float* __restrict__ bv, const int* __restrict__ mask,
    ushort* __restrict__ Qw, ushort* __restrict__ Kw, ushort* __restrict__ Vtw) {
  const int z = blockIdx.z;
  if (z == 0) {
    gemm_tile_body<2, 1>(q, Wt, bq, nullptr, (void*)Qw, blockIdx.x, blockIdx.y,
                         0.125f);
  } else if (z == 1) {
    gemm_tile_body<2, 1>(k, Wt + 262144, bk, nullptr, (void*)Kw, blockIdx.x,
                         blockIdx.y, 1.f);
  } else {
    gemm_tile_body<1, 1>(v, Wt + 2 * 262144, bv, mask, (void*)Vtw, blockIdx.x,
                         blockIdx.y, 1.f);
  }
}

// ============================================================================
// qrel_mfma: qrel[bh][i][r] = sum_d Q[bh][i][d]*rel[r][d] (fp32, stride
// NREL_PAD). Q pre-scaled by 1/8, rel scaled here by 8 -> identical values.
// ============================================================================
__global__ __launch_bounds__(256) void qrel_mfma(const ushort* __restrict__ Qw,
                                                 const float* __restrict__ rel,
                                                 float* __restrict__ qrel) {
  const int t = threadIdx.x;
  const int lane = t & 63, wave = t >> 6;
  const int m16 = lane & 15, quad = lane >> 4;
  const int r0 = blockIdx.x * 64;
  const int i0 = blockIdx.y * 64;
  const int bh = blockIdx.z;
  const ushort* Qb = Qw + ((size_t)bh * 2048 + i0 + (wave << 4) + m16) * 64;
  bf16x8 qa0 = *(const bf16x8*)(Qb + (quad << 3));
  bf16x8 qa1 = *(const bf16x8*)(Qb + 32 + (quad << 3));

  f32x4 acc[4] = {{0.f, 0.f, 0.f, 0.f}, {0.f, 0.f, 0.f, 0.f},
                  {0.f, 0.f, 0.f, 0.f}, {0.f, 0.f, 0.f, 0.f}};
#pragma unroll
  for (int rt = 0; rt < 4; ++rt) {
    int rr = min(r0 + (rt << 4) + m16, NREL - 1);
    const float* rp = rel + (size_t)rr * 64 + (quad << 3);
    float4 a0 = *(const float4*)rp,        a1 = *(const float4*)(rp + 4);
    float4 a2 = *(const float4*)(rp + 32), a3 = *(const float4*)(rp + 36);
    a0.x *= 8.f; a0.y *= 8.f; a0.z *= 8.f; a0.w *= 8.f;
    a1.x *= 8.f; a1.y *= 8.f; a1.z *= 8.f; a1.w *= 8.f;
    a2.x *= 8.f; a2.y *= 8.f; a2.z *= 8.f; a2.w *= 8.f;
    a3.x *= 8.f; a3.y *= 8.f; a3.z *= 8.f; a3.w *= 8.f;
    bf16x8 rf0 = pack8(a0, a1);
    bf16x8 rf1 = pack8(a2, a3);
    acc[rt] = __builtin_amdgcn_mfma_f32_16x16x32_bf16(qa0, rf0, acc[rt], 0, 0, 0);
    acc[rt] = __builtin_amdgcn_mfma_f32_16x16x32_bf16(qa1, rf1, acc[rt], 0, 0, 0);
  }
#pragma unroll
  for (int rt = 0; rt < 4; ++rt) {
    int r = r0 + (rt << 4) + m16;
    if (r < NREL_PAD) {
#pragma unroll
      for (int rg = 0; rg < 4; ++rg) {
        int i = i0 + (wave << 4) + (quad << 2) + rg;
        qrel[((size_t)bh * 2048 + i) * NREL_PAD + r] = acc[rt][rg];
      }
    }
  }
}

// ============================================================================
// qrel gather for one 64-j tile; wave-uniform clamp shortcut with hoisted
// edge values (zero loads on fully-clamped tiles).
// ============================================================================
__device__ __forceinline__ void gather_qv(float qv[4][4],
                                          const float* __restrict__ qrow,
                                          float e_lo, float e_hi,
                                          int iq, int iw0, int j0, int quad) {
  if (j0 - iw0 >= 264) {
#pragma unroll
    for (int jt = 0; jt < 4; ++jt)
#pragma unroll
      for (int r = 0; r < 4; ++r) qv[jt][r] = e_hi;
  } else if (iw0 - j0 >= 312) {
#pragma unroll
    for (int jt = 0; jt < 4; ++jt)
#pragma unroll
      for (int r = 0; r < 4; ++r) qv[jt][r] = e_lo;
  } else {
#pragma unroll
    for (int jt = 0; jt < 4; ++jt) {
#pragma unroll
      for (int r = 0; r < 4; ++r) {
        int j = j0 + (jt << 4) + (quad << 2) + r;
        int rr = min(NREL - 1, max(0, j - iq + 249));
        qv[jt][r] = qrow[rr];
      }
    }
  }
}

// ============================================================================
// Flash attention (R6 structure: LDS-staged K/V, reg prefetch, swapped QK^T,
// defer-max, XCD swizzle). SPLIT=1: grid (32,16,2), each block does half the
// j-range and writes unnormalized (O, m, l) partials -> combine_attn merges.
// Doubles resident blocks/CU (2 -> 4) to break barrier-lockstep idling.
// ============================================================================
template <int SPLIT>
__global__ __launch_bounds__(256) void flash_attn(
    const ushort* __restrict__ Qw, const ushort* __restrict__ Kw,
    const ushort* __restrict__ Vt, const float* __restrict__ qrel,
    const ushort* __restrict__ maskbf, ushort* __restrict__ attnbf,
    float* __restrict__ Opart, float* __restrict__ MLp) {
  __shared__ ushort QPs[64 * LDB];  // Q tile [i][d]; later P [i][j]
  __shared__ ushort Ks[64 * LDB];   // [j][d]
  __shared__ ushort Vs[64 * LDB];   // [d][j]
  const int t = threadIdx.x;
  const int lane = t & 63, wave = t >> 6;
  const int m16 = lane & 15, quad = lane >> 4;
  const int koff = quad << 3;
  const int bid = ((int)blockIdx.y << 5) + (int)blockIdx.x;
  const int swz = ((bid & 7) << 6) + (bid >> 3);  // XCD-contiguous chunks
  const int i0 = (swz & 31) << 6;
  const int bh = swz >> 5;
  const int b = bh >> 3, h = bh & 7;
  const int jstart = SPLIT ? ((int)blockIdx.z << 10) : 0;
  const int jend = SPLIT ? (jstart + 1024) : 2048;
  const ushort* Qb = Qw + (size_t)bh * 2048 * 64;
  const ushort* Kb = Kw + (size_t)bh * 2048 * 64;
  const ushort* Vb = Vt + (size_t)bh * 64 * 2048;
  const ushort* mbf = maskbf + b * 2048;
  const int iw0 = i0 + (wave << 4);
  const int iq = iw0 + m16;  // this lane's output row
  const float* qrow = qrel + ((size_t)bh * 2048 + iq) * NREL_PAD;
  const float e_lo = qrow[0], e_hi = qrow[NREL - 1];

  const int row0 = t >> 3, off0 = (t & 7) << 3;
  const int row1 = (t + 256) >> 3, off1 = ((t + 256) & 7) << 3;

  // Q tile -> LDS
  *(uint4*)&QPs[row0 * LDB + off0] =
      *(const uint4*)(Qb + (size_t)(i0 + row0) * 64 + off0);
  *(uint4*)&QPs[row1 * LDB + off1] =
      *(const uint4*)(Qb + (size_t)(i0 + row1) * 64 + off1);
  __syncthreads();

  bf16x8 qa0 = *(const bf16x8*)&QPs[((wave << 4) + m16) * LDB + koff];
  bf16x8 qa1 = *(const bf16x8*)&QPs[((wave << 4) + m16) * LDB + 32 + koff];

  // ---- prologue prefetch for j0 = jstart ----
  uint4 kr0 = *(const uint4*)(Kb + (size_t)(jstart + row0) * 64 + off0);
  uint4 kr1 = *(const uint4*)(Kb + (size_t)(jstart + row1) * 64 + off1);
  uint4 vr0 = *(const uint4*)(Vb + (size_t)row0 * 2048 + jstart + off0);
  uint4 vr1 = *(const uint4*)(Vb + (size_t)row1 * 2048 + jstart + off1);
  bf16x8 mfr0 = *(const bf16x8*)(mbf + jstart + koff);
  bf16x8 mfr1 = *(const bf16x8*)(mbf + jstart + 32 + koff);
  float qv[4][4];
  gather_qv(qv, qrow, e_lo, e_hi, iq, iw0, jstart, quad);

  float m_i = -INFINITY;
  f32x4 oacc[4];
  f32x4 lacc = {0.f, 0.f, 0.f, 0.f};
#pragma unroll
  for (int dt = 0; dt < 4; ++dt) oacc[dt] = (f32x4){0.f, 0.f, 0.f, 0.f};

  for (int j0 = jstart; j0 < jend; j0 += 64) {
    __syncthreads();
    *(uint4*)&Ks[row0 * LDB + off0] = kr0;
    *(uint4*)&Ks[row1 * LDB + off1] = kr1;
    *(uint4*)&Vs[row0 * LDB + off0] = vr0;
    *(uint4*)&Vs[row1 * LDB + off1] = vr1;
    __syncthreads();

    const int jn = (j0 + 64 < jend) ? (j0 + 64) : jstart;  // last-iter dummy
    uint4 kn0 = *(const uint4*)(Kb + (size_t)(jn + row0) * 64 + off0);
    uint4 kn1 = *(const uint4*)(Kb + (size_t)(jn + row1) * 64 + off1);
    uint4 vn0 = *(const uint4*)(Vb + (size_t)row0 * 2048 + jn + off0);
    uint4 vn1 = *(const uint4*)(Vb + (size_t)row1 * 2048 + jn + off1);
    bf16x8 mfn0 = *(const bf16x8*)(mbf + jn + koff);
    bf16x8 mfn1 = *(const bf16x8*)(mbf + jn + 32 + koff);
    float qn[4][4];
    gather_qv(qn, qrow, e_lo, e_hi, iq, iw0, jn, quad);

    // ---- QK^T, swapped, bias-initialized: sacc[jt][r] = S[iq][j] ----
    f32x4 sacc[4];
    __builtin_amdgcn_s_setprio(1);
#pragma unroll
    for (int jt = 0; jt < 4; ++jt) {
      bf16x8 kb0 = *(const bf16x8*)&Ks[((jt << 4) + m16) * LDB + koff];
      bf16x8 kb1 = *(const bf16x8*)&Ks[((jt << 4) + m16) * LDB + 32 + koff];
      f32x4 z = {qv[jt][0], qv[jt][1], qv[jt][2], qv[jt][3]};
      z = __builtin_amdgcn_mfma_f32_16x16x32_bf16(kb0, qa0, z, 0, 0, 0);
      z = __builtin_amdgcn_mfma_f32_16x16x32_bf16(kb1, qa1, z, 0, 0, 0);
      sacc[jt] = z;
    }
    __builtin_amdgcn_s_setprio(0);

    // ---- row max: in-register + 2 cross-quad shfl ----
    float t0 = fmaxf(fmaxf(sacc[0][0], sacc[0][1]), fmaxf(sacc[0][2], sacc[0][3]));
    float t1 = fmaxf(fmaxf(sacc[1][0], sacc[1][1]), fmaxf(sacc[1][2], sacc[1][3]));
    float t2 = fmaxf(fmaxf(sacc[2][0], sacc[2][1]), fmaxf(sacc[2][2], sacc[2][3]));
    float t3 = fmaxf(fmaxf(sacc[3][0], sacc[3][1]), fmaxf(sacc[3][2], sacc[3][3]));
    float mx = fmaxf(fmaxf(t0, t1), fmaxf(t2, t3));
    mx = fmaxf(mx, __shfl_xor(mx, 16));
    mx = fmaxf(mx, __shfl_xor(mx, 32));

    // ---- defer-max: rescale only on real growth (P bounded by e^8) ----
    if (__any(mx > m_i + 8.f)) {
      float mnew = fmaxf(m_i, mx);
      float al = __expf(m_i - mnew);
      m_i = mnew;
#pragma unroll
      for (int dt = 0; dt < 4; ++dt)
#pragma unroll
        for (int r = 0; r < 4; ++r) oacc[dt][r] *= al;
#pragma unroll
      for (int r = 0; r < 4; ++r) lacc[r] *= al;
    }

    // ---- P = exp(S - m_i) -> LDS (per-wave region, b64 runs) ----
    const int prow = ((wave << 4) + m16) * LDB;
#pragma unroll
    for (int jt = 0; jt < 4; ++jt) {
      ushort4 pk;
      pk.x = f2bf(__expf(sacc[jt][0] - m_i));
      pk.y = f2bf(__expf(sacc[jt][1] - m_i));
      pk.z = f2bf(__expf(sacc[jt][2] - m_i));
      pk.w = f2bf(__expf(sacc[jt][3] - m_i));
      *(ushort4*)&QPs[prow + (jt << 4) + (quad << 2)] = pk;
    }
    __asm__ volatile("s_waitcnt lgkmcnt(0)" ::: "memory");

    bf16x8 pa0 = *(const bf16x8*)&QPs[prow + koff];
    bf16x8 pa1 = *(const bf16x8*)&QPs[prow + 32 + koff];
    __builtin_amdgcn_s_setprio(1);
    lacc = __builtin_amdgcn_mfma_f32_16x16x32_bf16(mfr0, pa0, lacc, 0, 0, 0);
    lacc = __builtin_amdgcn_mfma_f32_16x16x32_bf16(mfr1, pa1, lacc, 0, 0, 0);
#pragma unroll
    for (int dt = 0; dt < 4; ++dt) {
      bf16x8 vb0 = *(const bf16x8*)&Vs[((dt << 4) + m16) * LDB + koff];
      bf16x8 vb1 = *(const bf16x8*)&Vs[((dt << 4) + m16) * LDB + 32 + koff];
      oacc[dt] = __builtin_amdgcn_mfma_f32_16x16x32_bf16(vb0, pa0, oacc[dt], 0, 0, 0);
      oacc[dt] = __builtin_amdgcn_mfma_f32_16x16x32_bf16(vb1, pa1, oacc[dt], 0, 0, 0);
    }
    __builtin_amdgcn_s_setprio(0);

    kr0 = kn0; kr1 = kn1; vr0 = vn0; vr1 = vn1;
    mfr0 = mfn0; mfr1 = mfn1;
#pragma unroll
    for (int jt = 0; jt < 4; ++jt)
#pragma unroll
      for (int r = 0; r < 4; ++r) qv[jt][r] = qn[jt][r];
  }

  if (SPLIT) {
    // unnormalized partials; lacc[0] == l_i (wave-uniform per m16 row)
    const size_t rb = ((size_t)(((int)blockIdx.z << 4) + bh) * 2048 + iq);
    float* dst = Opart + rb * 64;
#pragma unroll
    for (int dt = 0; dt < 4; ++dt) {
      float4 st;
      st.x = oacc[dt][0]; st.y = oacc[dt][1];
      st.z = oacc[dt][2]; st.w = oacc[dt][3];
      *(float4*)(dst + (dt << 4) + (quad << 2)) = st;
    }
    if (quad == 0) { MLp[rb * 2] = m_i; MLp[rb * 2 + 1] = lacc[0]; }
  } else {
    float inv = 1.0f / lacc[0];
    ushort* dst = attnbf + (size_t)(b * 2048 + iq) * 512 + h * 64;
#pragma unroll
    for (int dt = 0; dt < 4; ++dt) {
      ushort4 st;
      st.x = f2bf(oacc[dt][0] * inv);
      st.y = f2bf(oacc[dt][1] * inv);
      st.z = f2bf(oacc[dt][2] * inv);
      st.w = f2bf(oacc[dt][3] * inv);
      *(ushort4*)(dst + (dt << 4) + (quad << 2)) = st;
    }
  }
}

// ============================================================================
// combine_attn: merge the two j-half partials -> bf16 attn. Grid (32,16).
// out = (w0*O0 + w1*O1) / (w0*l0 + w1*l1), wz = exp(mz - max(m0,m1)).
// ============================================================================
__global__ __launch_bounds__(256) void combine_attn(
    const float* __restrict__ Opart, const float* __restrict__ MLp,
    ushort* __restrict__ attnbf) {
  const int t = threadIdx.x;
  const int i0 = blockIdx.x * 64, bh = blockIdx.y;
  const int b = bh >> 3, h = bh & 7;
  const int row = t >> 2, d0 = (t & 3) << 4;
  const int i = i0 + row;
  const size_t rb0 = (size_t)bh * 2048 + i;
  const size_t rb1 = (size_t)(16 + bh) * 2048 + i;
  float m0 = MLp[rb0 * 2], l0 = MLp[rb0 * 2 + 1];
  float m1 = MLp[rb1 * 2], l1 = MLp[rb1 * 2 + 1];
  float M = fmaxf(m0, m1);
  float w0 = __expf(m0 - M), w1 = __expf(m1 - M);
  float inv = 1.0f / (w0 * l0 + w1 * l1);
  const float* p0 = Opart + rb0 * 64 + d0;
  const float* p1 = Opart + rb1 * 64 + d0;
  ushort* dst = attnbf + ((size_t)(b * 2048) + i) * 512 + h * 64 + d0;
#pragma unroll
  for (int c = 0; c < 4; ++c) {
    float4 a = *(const float4*)(p0 + c * 4);
    float4 q = *(const float4*)(p1 + c * 4);
    ushort4 o;
    o.x = f2bf((w0 * a.x + w1 * q.x) * inv);
    o.y = f2bf((w0 * a.y + w1 * q.y) * inv);
    o.z = f2bf((w0 * a.z + w1 * q.z) * inv);
    o.w = f2bf((w0 * a.w + w1 * q.w) * inv);
    *(ushort4*)(dst + c * 4) = o;
  }
}

// ============================================================================
extern "C" void kernel_launch(void* const* d_in, const int* in_sizes, int n_in,
                              void* d_out, int out_size, void* d_ws,
                              size_t ws_size, hipStream_t stream) {
  const float* query = (const float*)d_in[0];
  const float* key   = (const float*)d_in[1];
  const float* value = (const float*)d_in[2];
  const int*   mask  = (const int*)d_in[3];
  const float* Wq = (const float*)d_in[4];
  const float* bq = (const float*)d_in[5];
  const float* Wk = (const float*)d_in[6];
  const float* bk = (const float*)d_in[7];
  const float* Wv = (const float*)d_in[8];
  const float* bv = (const float*)d_in[9];
  const float* Wo = (const float*)d_in[10];
  const float* bo = (const float*)d_in[11];
  const float* rel = (const float*)d_in[12];

  char* w = (char*)d_ws;
  size_t off = 0;
  ushort* Qw  = (ushort*)(w + off); off += (size_t)16 * 2048 * 64 * 2;       // 4 MB
  ushort* Kw  = (ushort*)(w + off); off += (size_t)16 * 2048 * 64 * 2;       // 4 MB
  ushort* Vtw = (ushort*)(w + off); off += (size_t)16 * 64 * 2048 * 2;       // 4 MB
  ushort* Wt  = (ushort*)(w + off); off += (size_t)4 * 512 * 512 * 2;        // 2 MB
  float* qrel = (float*)(w + off);  off += (size_t)16 * 2048 * NREL_PAD * 4; // 65.5 MB
  ushort* attnbf = (ushort*)(w + off); off += (size_t)4096 * 512 * 2;        // 4 MB
  ushort* maskbf = (ushort*)(w + off); off += (size_t)2 * 2048 * 2 + 8160;   // pad to 16 KB
  float* Opart = (float*)(w + off); off += (size_t)2 * 16 * 2048 * 64 * 4;   // 16 MB
  float* MLp  = (float*)(w + off);  off += (size_t)2 * 16 * 2048 * 2 * 4;    // 1 MB
  float* out = (float*)d_out;
  const bool split = (ws_size >= off);

  dim3 bb(256);
  hipLaunchKernelGGL(prep_wt, dim3(8, 8, 4), bb, 0, stream, Wq, Wk, Wv, Wo,
                     mask, Wt, maskbf);
  hipLaunchKernelGGL(gemm_qkv, dim3(8, 64, 3), bb, 0, stream, query, key, value,
                     Wt, bq, bk, bv, mask, Qw, Kw, Vtw);
  hipLaunchKernelGGL(qrel_mfma, dim3(8, 32, 16), bb, 0, stream, Qw, rel, qrel);
  if (split) {
    hipLaunchKernelGGL((flash_attn<1>), dim3(32, 16, 2), bb, 0, stream, Qw, Kw,
                       Vtw, qrel, maskbf, attnbf, Opart, MLp);
    hipLaunchKernelGGL(combine_attn, dim3(32, 16), bb, 0, stream, Opart, MLp,
                       attnbf);
  } else {
    hipLaunchKernelGGL((flash_attn<0>), dim3(32, 16), bb, 0, stream, Qw, Kw,
                       Vtw, qrel, maskbf, attnbf, (float*)attnbf,
                       (float*)attnbf);
  }
  hipLaunchKernelGGL((gemm_tile<0, 0>), dim3(8, 64), bb, 0, stream, attnbf,
                     Wt + 3 * 262144, bo, (void*)out);
}

// Round 9
// 219.124 us; speedup vs baseline: 1.3535x; 1.1072x over previous
//
#include <hip/hip_runtime.h>
#include <math.h>

// Problem constants
#define NREL 499        // 2*MAX_LEN-1
#define NREL_PAD 500    // row stride for qrel (2000 B, 16-B aligned)
#define LDB 72          // bf16 LDS row stride (flash kernel)
#define LDT 72          // bf16 LDS row stride (gemm tiles)

typedef __attribute__((ext_vector_type(8))) short bf16x8;
typedef __attribute__((ext_vector_type(4))) float f32x4;

__device__ __forceinline__ float bf2f(ushort x) {
  union { unsigned u; float f; } v; v.u = ((unsigned)x) << 16; return v.f;
}
__device__ __forceinline__ ushort f2bf(float x) {
  union { float f; unsigned u; } v; v.f = x;
  return (ushort)((v.u + 0x8000u) >> 16);
}
__device__ __forceinline__ bf16x8 pack8(float4 a, float4 b) {
  bf16x8 r;
  r[0] = (short)f2bf(a.x); r[1] = (short)f2bf(a.y);
  r[2] = (short)f2bf(a.z); r[3] = (short)f2bf(a.w);
  r[4] = (short)f2bf(b.x); r[5] = (short)f2bf(b.y);
  r[6] = (short)f2bf(b.z); r[7] = (short)f2bf(b.w);
  return r;
}

// ============================================================================
// prep_wt: Wt[z][n][k] (bf16) = W_z[k][n], z = {q,k,v,o}. Grid (8,8,4).
// Blocks (0,0,z): build maskbf[b][j] = mask ? 1.0bf : 0.0bf.
// Blocks (1,0,z): build rel8[512][64] bf16 = 8 * rel (rows >= 499 zeroed).
// ============================================================================
__global__ __launch_bounds__(256) void prep_wt(const float* __restrict__ W0,
                                               const float* __restrict__ W1,
                                               const float* __restrict__ W2,
                                               const float* __restrict__ W3,
                                               const int* __restrict__ mask,
                                               const float* __restrict__ rel,
                                               ushort* __restrict__ Wt,
                                               ushort* __restrict__ maskbf,
                                               ushort* __restrict__ rel8) {
  __shared__ float T[64][68];
  const int t = threadIdx.x;
  const int k0 = blockIdx.x * 64, n0 = blockIdx.y * 64, z = blockIdx.z;
  const float* W = (z == 0) ? W0 : (z == 1) ? W1 : (z == 2) ? W2 : W3;
#pragma unroll
  for (int s = 0; s < 4; ++s) {
    int idx = t + s * 256;
    int r = idx >> 4, c4 = (idx & 15) << 2;
    *(float4*)&T[r][c4] = *(const float4*)(W + (size_t)(k0 + r) * 512 + n0 + c4);
  }
  if (blockIdx.x == 0 && blockIdx.y == 0) {
    int base = z * 1024 + t * 4;
    int4 mv = *(const int4*)(mask + base);
    ushort4 mo;
    mo.x = mv.x ? 0x3F80 : 0; mo.y = mv.y ? 0x3F80 : 0;
    mo.z = mv.z ? 0x3F80 : 0; mo.w = mv.w ? 0x3F80 : 0;
    *(ushort4*)(maskbf + base) = mo;
  } else if (blockIdx.x == 1 && blockIdx.y == 0) {
    // rel8: 512*64 = 32768 bf16; 4 z-blocks x 256 thr x 32 each
    int base = z * 8192 + t * 32;
#pragma unroll
    for (int c = 0; c < 4; ++c) {
      ushort4 o;
      int e0 = base + c * 8;
      ushort tmp[8];
#pragma unroll
      for (int k = 0; k < 8; ++k) {
        int e = e0 + k;
        float v = (e < NREL * 64) ? rel[e] * 8.f : 0.f;
        tmp[k] = f2bf(v);
      }
      *(ushort4*)(rel8 + e0) = make_ushort4(tmp[0], tmp[1], tmp[2], tmp[3]);
      *(ushort4*)(rel8 + e0 + 4) = make_ushort4(tmp[4], tmp[5], tmp[6], tmp[7]);
    }
  }
  __syncthreads();
#pragma unroll
  for (int s = 0; s < 4; ++s) {
    int idx = t + s * 256;
    int row = idx >> 4, c4 = (idx & 15) << 2;  // row = n_local, c4 = k_local
    ushort4 u = make_ushort4(f2bf(T[c4 + 0][row]), f2bf(T[c4 + 1][row]),
                             f2bf(T[c4 + 2][row]), f2bf(T[c4 + 3][row]));
    *(ushort4*)(Wt + (size_t)z * 262144 + (size_t)(n0 + row) * 512 + k0 + c4) = u;
  }
}

// ============================================================================
// gemm_tile_body: C[64x64 tile] = A @ Wt^T(bf16 [n][k]) + bias.
// AFP32=1: A fp32, cast to bf16 during LDS staging (fused cast).
// MODE 0: fp32 row-major out [4096][512]               (output projection)
// MODE 1: bf16 Vt [bh][64 d][2048 l], masked columns zeroed (mvec)
// MODE 2: bf16 row-major head-split [bh][2048 l][64 d], scaled by oscale
// ============================================================================
template <int MODE, int AFP32>
__device__ __forceinline__ void gemm_tile_body(const void* __restrict__ Av,
                                               const ushort* __restrict__ Wt,
                                               const float* __restrict__ bias,
                                               const int* __restrict__ mvec,
                                               void* __restrict__ outv,
                                               int bx, int by, float oscale) {
  __shared__ ushort As[64 * LDT];
  __shared__ ushort Bs[64 * LDT];
  const int t = threadIdx.x;
  const int lane = t & 63, wave = t >> 6;
  const int m16 = lane & 15, quad = lane >> 4;
  const int koff = quad << 3;
  const int i0 = by * 64, n0 = bx * 64;
  const int row0 = t >> 3, off0 = (t & 7) << 3;
  const int row1 = (t + 256) >> 3, off1 = ((t + 256) & 7) << 3;
  const ushort* Ab16 = (const ushort*)Av + (size_t)i0 * 512;
  const float*  Ab32 = (const float*)Av + (size_t)i0 * 512;
  const ushort* Bb = Wt + (size_t)n0 * 512;

  uint4 ar0, ar1;
  float4 af00, af01, af10, af11;
  if (AFP32) {
    af00 = *(const float4*)(Ab32 + (size_t)row0 * 512 + off0);
    af01 = *(const float4*)(Ab32 + (size_t)row0 * 512 + off0 + 4);
    af10 = *(const float4*)(Ab32 + (size_t)row1 * 512 + off1);
    af11 = *(const float4*)(Ab32 + (size_t)row1 * 512 + off1 + 4);
  } else {
    ar0 = *(const uint4*)(Ab16 + (size_t)row0 * 512 + off0);
    ar1 = *(const uint4*)(Ab16 + (size_t)row1 * 512 + off1);
  }
  uint4 br0 = *(const uint4*)(Bb + (size_t)row0 * 512 + off0);
  uint4 br1 = *(const uint4*)(Bb + (size_t)row1 * 512 + off1);

  f32x4 acc[4] = {{0.f, 0.f, 0.f, 0.f}, {0.f, 0.f, 0.f, 0.f},
                  {0.f, 0.f, 0.f, 0.f}, {0.f, 0.f, 0.f, 0.f}};

  for (int ks = 0; ks < 8; ++ks) {
    __syncthreads();
    if (AFP32) {
      *(bf16x8*)&As[row0 * LDT + off0] = pack8(af00, af01);
      *(bf16x8*)&As[row1 * LDT + off1] = pack8(af10, af11);
    } else {
      *(uint4*)&As[row0 * LDT + off0] = ar0;
      *(uint4*)&As[row1 * LDT + off1] = ar1;
    }
    *(uint4*)&Bs[row0 * LDT + off0] = br0;
    *(uint4*)&Bs[row1 * LDT + off1] = br1;
    __syncthreads();

    const int kn = ((ks + 1) & 7) << 6;
    if (AFP32) {
      af00 = *(const float4*)(Ab32 + (size_t)row0 * 512 + kn + off0);
      af01 = *(const float4*)(Ab32 + (size_t)row0 * 512 + kn + off0 + 4);
      af10 = *(const float4*)(Ab32 + (size_t)row1 * 512 + kn + off1);
      af11 = *(const float4*)(Ab32 + (size_t)row1 * 512 + kn + off1 + 4);
    } else {
      ar0 = *(const uint4*)(Ab16 + (size_t)row0 * 512 + kn + off0);
      ar1 = *(const uint4*)(Ab16 + (size_t)row1 * 512 + kn + off1);
    }
    br0 = *(const uint4*)(Bb + (size_t)row0 * 512 + kn + off0);
    br1 = *(const uint4*)(Bb + (size_t)row1 * 512 + kn + off1);

    __builtin_amdgcn_s_setprio(1);
    if (MODE != 1) {
#pragma unroll
      for (int kh = 0; kh < 2; ++kh) {
        bf16x8 af = *(const bf16x8*)&As[((wave << 4) + m16) * LDT + (kh << 5) + koff];
#pragma unroll
        for (int nt = 0; nt < 4; ++nt) {
          bf16x8 wf = *(const bf16x8*)&Bs[((nt << 4) + m16) * LDT + (kh << 5) + koff];
          acc[nt] = __builtin_amdgcn_mfma_f32_16x16x32_bf16(af, wf, acc[nt], 0, 0, 0);
        }
      }
    } else {
#pragma unroll
      for (int kh = 0; kh < 2; ++kh) {
        bf16x8 wf = *(const bf16x8*)&Bs[((wave << 4) + m16) * LDT + (kh << 5) + koff];
#pragma unroll
        for (int it = 0; it < 4; ++it) {
          bf16x8 af = *(const bf16x8*)&As[((it << 4) + m16) * LDT + (kh << 5) + koff];
          acc[it] = __builtin_amdgcn_mfma_f32_16x16x32_bf16(wf, af, acc[it], 0, 0, 0);
        }
      }
    }
    __builtin_amdgcn_s_setprio(0);
  }

  if (MODE == 0) {
    float* out = (float*)outv;
#pragma unroll
    for (int nt = 0; nt < 4; ++nt) {
      float bn = bias[n0 + (nt << 4) + m16];
#pragma unroll
      for (int r = 0; r < 4; ++r) {
        int i = i0 + (wave << 4) + (quad << 2) + r;
        out[(size_t)i * 512 + n0 + (nt << 4) + m16] = acc[nt][r] + bn;
      }
    }
  } else if (MODE == 2) {
    ushort* out = (ushort*)outv;
    const int b = i0 >> 11, l0 = i0 & 2047, h = n0 >> 6;
#pragma unroll
    for (int nt = 0; nt < 4; ++nt) {
      float bn = bias[n0 + (nt << 4) + m16];
      int d = (nt << 4) + m16;
#pragma unroll
      for (int r = 0; r < 4; ++r) {
        int il = (wave << 4) + (quad << 2) + r;
        out[((size_t)(b * 8 + h) * 2048 + l0 + il) * 64 + d] =
            f2bf((acc[nt][r] + bn) * oscale);
      }
    }
  } else {  // MODE 1: Vt [bh][d][l], masked columns -> 0
    ushort* out = (ushort*)outv;
    const int b = i0 >> 11, l0 = i0 & 2047, h = n0 >> 6;
    float4 b4 = *(const float4*)(bias + n0 + (wave << 4) + (quad << 2));
    float bb[4] = {b4.x, b4.y, b4.z, b4.w};
    float mkf[4];
#pragma unroll
    for (int it = 0; it < 4; ++it)
      mkf[it] = (mvec[b * 2048 + l0 + (it << 4) + m16] != 0) ? 1.f : 0.f;
#pragma unroll
    for (int r = 0; r < 4; ++r) {
      int d = (wave << 4) + (quad << 2) + r;
#pragma unroll
      for (int it = 0; it < 4; ++it) {
        out[((size_t)(b * 8 + h) * 64 + d) * 2048 + l0 + (it << 4) + m16] =
            f2bf((acc[it][r] + bb[r]) * mkf[it]);
      }
    }
  }
}

template <int MODE, int AFP32>
__global__ __launch_bounds__(256) void gemm_tile(const void* __restrict__ A,
                                                 const ushort* __restrict__ Wt,
                                                 const float* __restrict__ bias,
                                                 void* __restrict__ outv) {
  gemm_tile_body<MODE, AFP32>(A, Wt, bias, nullptr, outv, blockIdx.x,
                              blockIdx.y, 1.f);
}

// Merged QKV projection with fused fp32->bf16 A staging. Grid (8, 64, 3).
// Q output pre-scaled by 0.125 (exact in bf16); rel pre-scaled by 8 so qrel
// values are bitwise unchanged.
__global__ __launch_bounds__(256) void gemm_qkv(
    const float* __restrict__ q, const float* __restrict__ k,
    const float* __restrict__ v, const ushort* __restrict__ Wt,
    const float* __restrict__ bq, const float* __restrict__ bk,
    const float* __restrict__ bv, const int* __restrict__ mask,
    ushort* __restrict__ Qw, ushort* __restrict__ Kw, ushort* __restrict__ Vtw) {
  const int z = blockIdx.z;
  if (z == 0) {
    gemm_tile_body<2, 1>(q, Wt, bq, nullptr, (void*)Qw, blockIdx.x, blockIdx.y,
                         0.125f);
  } else if (z == 1) {
    gemm_tile_body<2, 1>(k, Wt + 262144, bk, nullptr, (void*)Kw, blockIdx.x,
                         blockIdx.y, 1.f);
  } else {
    gemm_tile_body<1, 1>(v, Wt + 2 * 262144, bv, mask, (void*)Vtw, blockIdx.x,
                         blockIdx.y, 1.f);
  }
}

// ============================================================================
// qrel_tile: qrel[bh][i][r] = sum_d Q[bh][i][d]*rel8[r][d] (fp32, stride
// NREL_PAD). LDS-tiled single-K-step GEMM (K=64): stage Q-tile + rel8-tile,
// one barrier, 8 MFMAs/wave, store. Grid (8, 32, 16). rel8 is bf16 (prepped),
// rows >= 499 are zero (so the pad column 499 gets 0; flash never reads it).
// ============================================================================
__global__ __launch_bounds__(256) void qrel_tile(const ushort* __restrict__ Qw,
                                                 const ushort* __restrict__ rel8,
                                                 float* __restrict__ qrel) {
  __shared__ ushort As[64 * LDT];
  __shared__ ushort Bs[64 * LDT];
  const int t = threadIdx.x;
  const int lane = t & 63, wave = t >> 6;
  const int m16 = lane & 15, quad = lane >> 4;
  const int koff = quad << 3;
  const int r0 = blockIdx.x * 64;
  const int i0 = blockIdx.y * 64;
  const int bh = blockIdx.z;
  const int row0 = t >> 3, off0 = (t & 7) << 3;
  const int row1 = (t + 256) >> 3, off1 = ((t + 256) & 7) << 3;

  *(uint4*)&As[row0 * LDT + off0] =
      *(const uint4*)(Qw + ((size_t)bh * 2048 + i0 + row0) * 64 + off0);
  *(uint4*)&As[row1 * LDT + off1] =
      *(const uint4*)(Qw + ((size_t)bh * 2048 + i0 + row1) * 64 + off1);
  *(uint4*)&Bs[row0 * LDT + off0] =
      *(const uint4*)(rel8 + (size_t)(r0 + row0) * 64 + off0);
  *(uint4*)&Bs[row1 * LDT + off1] =
      *(const uint4*)(rel8 + (size_t)(r0 + row1) * 64 + off1);
  __syncthreads();

  f32x4 acc[4] = {{0.f, 0.f, 0.f, 0.f}, {0.f, 0.f, 0.f, 0.f},
                  {0.f, 0.f, 0.f, 0.f}, {0.f, 0.f, 0.f, 0.f}};
#pragma unroll
  for (int kh = 0; kh < 2; ++kh) {
    bf16x8 af = *(const bf16x8*)&As[((wave << 4) + m16) * LDT + (kh << 5) + koff];
#pragma unroll
    for (int nt = 0; nt < 4; ++nt) {
      bf16x8 wf = *(const bf16x8*)&Bs[((nt << 4) + m16) * LDT + (kh << 5) + koff];
      acc[nt] = __builtin_amdgcn_mfma_f32_16x16x32_bf16(af, wf, acc[nt], 0, 0, 0);
    }
  }

#pragma unroll
  for (int nt = 0; nt < 4; ++nt) {
    int r = r0 + (nt << 4) + m16;
    if (r < NREL_PAD) {
#pragma unroll
      for (int rg = 0; rg < 4; ++rg) {
        int i = i0 + (wave << 4) + (quad << 2) + rg;
        qrel[((size_t)bh * 2048 + i) * NREL_PAD + r] = acc[nt][rg];
      }
    }
  }
}

// ============================================================================
// qrel gather for one 64-j tile; wave-uniform clamp shortcut with hoisted
// edge values (zero loads on fully-clamped tiles).
// ============================================================================
__device__ __forceinline__ void gather_qv(float qv[4][4],
                                          const float* __restrict__ qrow,
                                          float e_lo, float e_hi,
                                          int iq, int iw0, int j0, int quad) {
  if (j0 - iw0 >= 264) {
#pragma unroll
    for (int jt = 0; jt < 4; ++jt)
#pragma unroll
      for (int r = 0; r < 4; ++r) qv[jt][r] = e_hi;
  } else if (iw0 - j0 >= 312) {
#pragma unroll
    for (int jt = 0; jt < 4; ++jt)
#pragma unroll
      for (int r = 0; r < 4; ++r) qv[jt][r] = e_lo;
  } else {
#pragma unroll
    for (int jt = 0; jt < 4; ++jt) {
#pragma unroll
      for (int r = 0; r < 4; ++r) {
        int j = j0 + (jt << 4) + (quad << 2) + r;
        int rr = min(NREL - 1, max(0, j - iq + 249));
        qv[jt][r] = qrow[rr];
      }
    }
  }
}

// ============================================================================
// Flash attention (R6 structure, best measured: 77.4 us): LDS-staged K/V,
// register prefetch, swapped-operand QK^T with bias-initialized C, in-register
// softmax, defer-max, MFMA l-accumulation, XCD-aware block swizzle.
// ============================================================================
__global__ __launch_bounds__(256) void flash_attn(
    const ushort* __restrict__ Qw, const ushort* __restrict__ Kw,
    const ushort* __restrict__ Vt, const float* __restrict__ qrel,
    const ushort* __restrict__ maskbf, ushort* __restrict__ attnbf) {
  __shared__ ushort QPs[64 * LDB];  // Q tile [i][d]; later P [i][j]
  __shared__ ushort Ks[64 * LDB];   // [j][d]
  __shared__ ushort Vs[64 * LDB];   // [d][j]
  const int t = threadIdx.x;
  const int lane = t & 63, wave = t >> 6;
  const int m16 = lane & 15, quad = lane >> 4;
  const int koff = quad << 3;
  const int bid = ((int)blockIdx.y << 5) + (int)blockIdx.x;
  const int swz = ((bid & 7) << 6) + (bid >> 3);  // XCD-contiguous chunks
  const int i0 = (swz & 31) << 6;
  const int bh = swz >> 5;
  const int b = bh >> 3, h = bh & 7;
  const ushort* Qb = Qw + (size_t)bh * 2048 * 64;
  const ushort* Kb = Kw + (size_t)bh * 2048 * 64;
  const ushort* Vb = Vt + (size_t)bh * 64 * 2048;
  const ushort* mbf = maskbf + b * 2048;
  const int iw0 = i0 + (wave << 4);
  const int iq = iw0 + m16;  // this lane's output row
  const float* qrow = qrel + ((size_t)bh * 2048 + iq) * NREL_PAD;
  const float e_lo = qrow[0], e_hi = qrow[NREL - 1];

  const int row0 = t >> 3, off0 = (t & 7) << 3;
  const int row1 = (t + 256) >> 3, off1 = ((t + 256) & 7) << 3;

  // Q tile -> LDS
  *(uint4*)&QPs[row0 * LDB + off0] =
      *(const uint4*)(Qb + (size_t)(i0 + row0) * 64 + off0);
  *(uint4*)&QPs[row1 * LDB + off1] =
      *(const uint4*)(Qb + (size_t)(i0 + row1) * 64 + off1);
  __syncthreads();

  bf16x8 qa0 = *(const bf16x8*)&QPs[((wave << 4) + m16) * LDB + koff];
  bf16x8 qa1 = *(const bf16x8*)&QPs[((wave << 4) + m16) * LDB + 32 + koff];

  // ---- prologue prefetch for j0 = 0 ----
  uint4 kr0 = *(const uint4*)(Kb + (size_t)row0 * 64 + off0);
  uint4 kr1 = *(const uint4*)(Kb + (size_t)row1 * 64 + off1);
  uint4 vr0 = *(const uint4*)(Vb + (size_t)row0 * 2048 + off0);
  uint4 vr1 = *(const uint4*)(Vb + (size_t)row1 * 2048 + off1);
  bf16x8 mfr0 = *(const bf16x8*)(mbf + koff);
  bf16x8 mfr1 = *(const bf16x8*)(mbf + 32 + koff);
  float qv[4][4];
  gather_qv(qv, qrow, e_lo, e_hi, iq, iw0, 0, quad);

  float m_i = -INFINITY;
  f32x4 oacc[4];
  f32x4 lacc = {0.f, 0.f, 0.f, 0.f};
#pragma unroll
  for (int dt = 0; dt < 4; ++dt) oacc[dt] = (f32x4){0.f, 0.f, 0.f, 0.f};

  for (int j0 = 0; j0 < 2048; j0 += 64) {
    __syncthreads();
    *(uint4*)&Ks[row0 * LDB + off0] = kr0;
    *(uint4*)&Ks[row1 * LDB + off1] = kr1;
    *(uint4*)&Vs[row0 * LDB + off0] = vr0;
    *(uint4*)&Vs[row1 * LDB + off1] = vr1;
    __syncthreads();

    const int jn = (j0 + 64) & 2047;  // wraps on last iter (unused)
    uint4 kn0 = *(const uint4*)(Kb + (size_t)(jn + row0) * 64 + off0);
    uint4 kn1 = *(const uint4*)(Kb + (size_t)(jn + row1) * 64 + off1);
    uint4 vn0 = *(const uint4*)(Vb + (size_t)row0 * 2048 + jn + off0);
    uint4 vn1 = *(const uint4*)(Vb + (size_t)row1 * 2048 + jn + off1);
    bf16x8 mfn0 = *(const bf16x8*)(mbf + jn + koff);
    bf16x8 mfn1 = *(const bf16x8*)(mbf + jn + 32 + koff);
    float qn[4][4];
    gather_qv(qn, qrow, e_lo, e_hi, iq, iw0, jn, quad);

    // ---- QK^T, swapped, bias-initialized: sacc[jt][r] = S[iq][j] ----
    f32x4 sacc[4];
    __builtin_amdgcn_s_setprio(1);
#pragma unroll
    for (int jt = 0; jt < 4; ++jt) {
      bf16x8 kb0 = *(const bf16x8*)&Ks[((jt << 4) + m16) * LDB + koff];
      bf16x8 kb1 = *(const bf16x8*)&Ks[((jt << 4) + m16) * LDB + 32 + koff];
      f32x4 z = {qv[jt][0], qv[jt][1], qv[jt][2], qv[jt][3]};
      z = __builtin_amdgcn_mfma_f32_16x16x32_bf16(kb0, qa0, z, 0, 0, 0);
      z = __builtin_amdgcn_mfma_f32_16x16x32_bf16(kb1, qa1, z, 0, 0, 0);
      sacc[jt] = z;
    }
    __builtin_amdgcn_s_setprio(0);

    // ---- row max: in-register + 2 cross-quad shfl ----
    float t0 = fmaxf(fmaxf(sacc[0][0], sacc[0][1]), fmaxf(sacc[0][2], sacc[0][3]));
    float t1 = fmaxf(fmaxf(sacc[1][0], sacc[1][1]), fmaxf(sacc[1][2], sacc[1][3]));
    float t2 = fmaxf(fmaxf(sacc[2][0], sacc[2][1]), fmaxf(sacc[2][2], sacc[2][3]));
    float t3 = fmaxf(fmaxf(sacc[3][0], sacc[3][1]), fmaxf(sacc[3][2], sacc[3][3]));
    float mx = fmaxf(fmaxf(t0, t1), fmaxf(t2, t3));
    mx = fmaxf(mx, __shfl_xor(mx, 16));
    mx = fmaxf(mx, __shfl_xor(mx, 32));

    // ---- defer-max: rescale only on real growth (P bounded by e^8) ----
    if (__any(mx > m_i + 8.f)) {
      float mnew = fmaxf(m_i, mx);
      float al = __expf(m_i - mnew);
      m_i = mnew;
#pragma unroll
      for (int dt = 0; dt < 4; ++dt)
#pragma unroll
        for (int r = 0; r < 4; ++r) oacc[dt][r] *= al;
#pragma unroll
      for (int r = 0; r < 4; ++r) lacc[r] *= al;
    }

    // ---- P = exp(S - m_i) -> LDS (per-wave region, b64 runs) ----
    const int prow = ((wave << 4) + m16) * LDB;
#pragma unroll
    for (int jt = 0; jt < 4; ++jt) {
      ushort4 pk;
      pk.x = f2bf(__expf(sacc[jt][0] - m_i));
      pk.y = f2bf(__expf(sacc[jt][1] - m_i));
      pk.z = f2bf(__expf(sacc[jt][2] - m_i));
      pk.w = f2bf(__expf(sacc[jt][3] - m_i));
      *(ushort4*)&QPs[prow + (jt << 4) + (quad << 2)] = pk;
    }
    __asm__ volatile("s_waitcnt lgkmcnt(0)" ::: "memory");

    bf16x8 pa0 = *(const bf16x8*)&QPs[prow + koff];
    bf16x8 pa1 = *(const bf16x8*)&QPs[prow + 32 + koff];
    __builtin_amdgcn_s_setprio(1);
    lacc = __builtin_amdgcn_mfma_f32_16x16x32_bf16(mfr0, pa0, lacc, 0, 0, 0);
    lacc = __builtin_amdgcn_mfma_f32_16x16x32_bf16(mfr1, pa1, lacc, 0, 0, 0);
#pragma unroll
    for (int dt = 0; dt < 4; ++dt) {
      bf16x8 vb0 = *(const bf16x8*)&Vs[((dt << 4) + m16) * LDB + koff];
      bf16x8 vb1 = *(const bf16x8*)&Vs[((dt << 4) + m16) * LDB + 32 + koff];
      oacc[dt] = __builtin_amdgcn_mfma_f32_16x16x32_bf16(vb0, pa0, oacc[dt], 0, 0, 0);
      oacc[dt] = __builtin_amdgcn_mfma_f32_16x16x32_bf16(vb1, pa1, oacc[dt], 0, 0, 0);
    }
    __builtin_amdgcn_s_setprio(0);

    kr0 = kn0; kr1 = kn1; vr0 = vn0; vr1 = vn1;
    mfr0 = mfn0; mfr1 = mfn1;
#pragma unroll
    for (int jt = 0; jt < 4; ++jt)
#pragma unroll
      for (int r = 0; r < 4; ++r) qv[jt][r] = qn[jt][r];
  }

  // epilogue: lane holds O[iq][d = dt*16 + quad*4 + r]; l = lacc[0]
  float inv = 1.0f / lacc[0];
  ushort* dst = attnbf + (size_t)(b * 2048 + iq) * 512 + h * 64;
#pragma unroll
  for (int dt = 0; dt < 4; ++dt) {
    ushort4 st;
    st.x = f2bf(oacc[dt][0] * inv);
    st.y = f2bf(oacc[dt][1] * inv);
    st.z = f2bf(oacc[dt][2] * inv);
    st.w = f2bf(oacc[dt][3] * inv);
    *(ushort4*)(dst + (dt << 4) + (quad << 2)) = st;
  }
}

// ============================================================================
extern "C" void kernel_launch(void* const* d_in, const int* in_sizes, int n_in,
                              void* d_out, int out_size, void* d_ws,
                              size_t ws_size, hipStream_t stream) {
  const float* query = (const float*)d_in[0];
  const float* key   = (const float*)d_in[1];
  const float* value = (const float*)d_in[2];
  const int*   mask  = (const int*)d_in[3];
  const float* Wq = (const float*)d_in[4];
  const float* bq = (const float*)d_in[5];
  const float* Wk = (const float*)d_in[6];
  const float* bk = (const float*)d_in[7];
  const float* Wv = (const float*)d_in[8];
  const float* bv = (const float*)d_in[9];
  const float* Wo = (const float*)d_in[10];
  const float* bo = (const float*)d_in[11];
  const float* rel = (const float*)d_in[12];

  char* w = (char*)d_ws;
  size_t off = 0;
  ushort* Qw  = (ushort*)(w + off); off += (size_t)16 * 2048 * 64 * 2;       // 4 MB
  ushort* Kw  = (ushort*)(w + off); off += (size_t)16 * 2048 * 64 * 2;       // 4 MB
  ushort* Vtw = (ushort*)(w + off); off += (size_t)16 * 64 * 2048 * 2;       // 4 MB
  ushort* Wt  = (ushort*)(w + off); off += (size_t)4 * 512 * 512 * 2;        // 2 MB
  float* qrel = (float*)(w + off);  off += (size_t)16 * 2048 * NREL_PAD * 4; // 65.5 MB
  ushort* attnbf = (ushort*)(w + off); off += (size_t)4096 * 512 * 2;        // 4 MB
  ushort* maskbf = (ushort*)(w + off); off += (size_t)2 * 2048 * 2;          // 8 KB
  ushort* rel8 = (ushort*)(w + off); off += (size_t)512 * 64 * 2;            // 64 KB
  float* out = (float*)d_out;

  dim3 bb(256);
  hipLaunchKernelGGL(prep_wt, dim3(8, 8, 4), bb, 0, stream, Wq, Wk, Wv, Wo,
                     mask, rel, Wt, maskbf, rel8);
  hipLaunchKernelGGL(gemm_qkv, dim3(8, 64, 3), bb, 0, stream, query, key, value,
                     Wt, bq, bk, bv, mask, Qw, Kw, Vtw);
  hipLaunchKernelGGL(qrel_tile, dim3(8, 32, 16), bb, 0, stream, Qw, rel8, qrel);
  hipLaunchKernelGGL(flash_attn, dim3(32, 16), bb, 0, stream, Qw, Kw, Vtw, qrel,
                     maskbf, attnbf);
  hipLaunchKernelGGL((gemm_tile<0, 0>), dim3(8, 64), bb, 0, stream, attnbf,
                     Wt + 3 * 262144, bo, (void*)out);
}

// Round 10
// 212.683 us; speedup vs baseline: 1.3945x; 1.0303x over previous
//
#include <hip/hip_runtime.h>
#include <math.h>

// Problem constants
#define NREL 499        // 2*MAX_LEN-1
#define NREL_PAD 500    // row stride for qrel (1000 B fp16)
#define LDB 72          // bf16 LDS row stride (flash kernel)
#define LDT 72          // bf16 LDS row stride (gemm tiles)

typedef __attribute__((ext_vector_type(8))) short bf16x8;
typedef __attribute__((ext_vector_type(4))) float f32x4;

__device__ __forceinline__ float bf2f(ushort x) {
  union { unsigned u; float f; } v; v.u = ((unsigned)x) << 16; return v.f;
}
__device__ __forceinline__ ushort f2bf(float x) {
  union { float f; unsigned u; } v; v.f = x;
  return (ushort)((v.u + 0x8000u) >> 16);
}
__device__ __forceinline__ ushort f2h(float x) {
  union { _Float16 h; ushort u; } v; v.h = (_Float16)x; return v.u;
}
__device__ __forceinline__ float h2f(ushort u) {
  union { _Float16 h; ushort u; } v; v.u = u; return (float)v.h;
}
__device__ __forceinline__ bf16x8 pack8(float4 a, float4 b) {
  bf16x8 r;
  r[0] = (short)f2bf(a.x); r[1] = (short)f2bf(a.y);
  r[2] = (short)f2bf(a.z); r[3] = (short)f2bf(a.w);
  r[4] = (short)f2bf(b.x); r[5] = (short)f2bf(b.y);
  r[6] = (short)f2bf(b.z); r[7] = (short)f2bf(b.w);
  return r;
}

// ============================================================================
// prep_wt: Wt[z][n][k] (bf16) = W_z[k][n], z = {q,k,v,o}. Grid (8,8,4).
// Blocks (0,0,z): build maskbf[b][j] = mask ? 1.0bf : 0.0bf.
// Blocks (1,0,z): build rel8[512][64] bf16 = 8 * rel (rows >= 499 zeroed).
// ============================================================================
__global__ __launch_bounds__(256) void prep_wt(const float* __restrict__ W0,
                                               const float* __restrict__ W1,
                                               const float* __restrict__ W2,
                                               const float* __restrict__ W3,
                                               const int* __restrict__ mask,
                                               const float* __restrict__ rel,
                                               ushort* __restrict__ Wt,
                                               ushort* __restrict__ maskbf,
                                               ushort* __restrict__ rel8) {
  __shared__ float T[64][68];
  const int t = threadIdx.x;
  const int k0 = blockIdx.x * 64, n0 = blockIdx.y * 64, z = blockIdx.z;
  const float* W = (z == 0) ? W0 : (z == 1) ? W1 : (z == 2) ? W2 : W3;
#pragma unroll
  for (int s = 0; s < 4; ++s) {
    int idx = t + s * 256;
    int r = idx >> 4, c4 = (idx & 15) << 2;
    *(float4*)&T[r][c4] = *(const float4*)(W + (size_t)(k0 + r) * 512 + n0 + c4);
  }
  if (blockIdx.x == 0 && blockIdx.y == 0) {
    int base = z * 1024 + t * 4;
    int4 mv = *(const int4*)(mask + base);
    ushort4 mo;
    mo.x = mv.x ? 0x3F80 : 0; mo.y = mv.y ? 0x3F80 : 0;
    mo.z = mv.z ? 0x3F80 : 0; mo.w = mv.w ? 0x3F80 : 0;
    *(ushort4*)(maskbf + base) = mo;
  } else if (blockIdx.x == 1 && blockIdx.y == 0) {
    // rel8: 512*64 = 32768 bf16; 4 z-blocks x 256 thr x 32 each
    int base = z * 8192 + t * 32;
#pragma unroll
    for (int c = 0; c < 4; ++c) {
      int e0 = base + c * 8;
      ushort tmp[8];
#pragma unroll
      for (int k = 0; k < 8; ++k) {
        int e = e0 + k;
        float v = (e < NREL * 64) ? rel[e] * 8.f : 0.f;
        tmp[k] = f2bf(v);
      }
      *(ushort4*)(rel8 + e0) = make_ushort4(tmp[0], tmp[1], tmp[2], tmp[3]);
      *(ushort4*)(rel8 + e0 + 4) = make_ushort4(tmp[4], tmp[5], tmp[6], tmp[7]);
    }
  }
  __syncthreads();
#pragma unroll
  for (int s = 0; s < 4; ++s) {
    int idx = t + s * 256;
    int row = idx >> 4, c4 = (idx & 15) << 2;  // row = n_local, c4 = k_local
    ushort4 u = make_ushort4(f2bf(T[c4 + 0][row]), f2bf(T[c4 + 1][row]),
                             f2bf(T[c4 + 2][row]), f2bf(T[c4 + 3][row]));
    *(ushort4*)(Wt + (size_t)z * 262144 + (size_t)(n0 + row) * 512 + k0 + c4) = u;
  }
}

// ============================================================================
// gemm_tile_body: C[64x64 tile] = A @ Wt^T(bf16 [n][k]) + bias.
// AFP32=1: A fp32, cast to bf16 during LDS staging (fused cast).
// MODE 0: fp32 row-major out [4096][512]               (output projection)
// MODE 1: bf16 Vt [bh][64 d][2048 l], masked columns zeroed (mvec)
// MODE 2: bf16 row-major head-split [bh][2048 l][64 d], scaled by oscale
// ============================================================================
template <int MODE, int AFP32>
__device__ __forceinline__ void gemm_tile_body(const void* __restrict__ Av,
                                               const ushort* __restrict__ Wt,
                                               const float* __restrict__ bias,
                                               const int* __restrict__ mvec,
                                               void* __restrict__ outv,
                                               int bx, int by, float oscale) {
  __shared__ ushort As[64 * LDT];
  __shared__ ushort Bs[64 * LDT];
  const int t = threadIdx.x;
  const int lane = t & 63, wave = t >> 6;
  const int m16 = lane & 15, quad = lane >> 4;
  const int koff = quad << 3;
  const int i0 = by * 64, n0 = bx * 64;
  const int row0 = t >> 3, off0 = (t & 7) << 3;
  const int row1 = (t + 256) >> 3, off1 = ((t + 256) & 7) << 3;
  const ushort* Ab16 = (const ushort*)Av + (size_t)i0 * 512;
  const float*  Ab32 = (const float*)Av + (size_t)i0 * 512;
  const ushort* Bb = Wt + (size_t)n0 * 512;

  uint4 ar0, ar1;
  float4 af00, af01, af10, af11;
  if (AFP32) {
    af00 = *(const float4*)(Ab32 + (size_t)row0 * 512 + off0);
    af01 = *(const float4*)(Ab32 + (size_t)row0 * 512 + off0 + 4);
    af10 = *(const float4*)(Ab32 + (size_t)row1 * 512 + off1);
    af11 = *(const float4*)(Ab32 + (size_t)row1 * 512 + off1 + 4);
  } else {
    ar0 = *(const uint4*)(Ab16 + (size_t)row0 * 512 + off0);
    ar1 = *(const uint4*)(Ab16 + (size_t)row1 * 512 + off1);
  }
  uint4 br0 = *(const uint4*)(Bb + (size_t)row0 * 512 + off0);
  uint4 br1 = *(const uint4*)(Bb + (size_t)row1 * 512 + off1);

  f32x4 acc[4] = {{0.f, 0.f, 0.f, 0.f}, {0.f, 0.f, 0.f, 0.f},
                  {0.f, 0.f, 0.f, 0.f}, {0.f, 0.f, 0.f, 0.f}};

  for (int ks = 0; ks < 8; ++ks) {
    __syncthreads();
    if (AFP32) {
      *(bf16x8*)&As[row0 * LDT + off0] = pack8(af00, af01);
      *(bf16x8*)&As[row1 * LDT + off1] = pack8(af10, af11);
    } else {
      *(uint4*)&As[row0 * LDT + off0] = ar0;
      *(uint4*)&As[row1 * LDT + off1] = ar1;
    }
    *(uint4*)&Bs[row0 * LDT + off0] = br0;
    *(uint4*)&Bs[row1 * LDT + off1] = br1;
    __syncthreads();

    const int kn = ((ks + 1) & 7) << 6;
    if (AFP32) {
      af00 = *(const float4*)(Ab32 + (size_t)row0 * 512 + kn + off0);
      af01 = *(const float4*)(Ab32 + (size_t)row0 * 512 + kn + off0 + 4);
      af10 = *(const float4*)(Ab32 + (size_t)row1 * 512 + kn + off1);
      af11 = *(const float4*)(Ab32 + (size_t)row1 * 512 + kn + off1 + 4);
    } else {
      ar0 = *(const uint4*)(Ab16 + (size_t)row0 * 512 + kn + off0);
      ar1 = *(const uint4*)(Ab16 + (size_t)row1 * 512 + kn + off1);
    }
    br0 = *(const uint4*)(Bb + (size_t)row0 * 512 + kn + off0);
    br1 = *(const uint4*)(Bb + (size_t)row1 * 512 + kn + off1);

    __builtin_amdgcn_s_setprio(1);
    if (MODE != 1) {
#pragma unroll
      for (int kh = 0; kh < 2; ++kh) {
        bf16x8 af = *(const bf16x8*)&As[((wave << 4) + m16) * LDT + (kh << 5) + koff];
#pragma unroll
        for (int nt = 0; nt < 4; ++nt) {
          bf16x8 wf = *(const bf16x8*)&Bs[((nt << 4) + m16) * LDT + (kh << 5) + koff];
          acc[nt] = __builtin_amdgcn_mfma_f32_16x16x32_bf16(af, wf, acc[nt], 0, 0, 0);
        }
      }
    } else {
#pragma unroll
      for (int kh = 0; kh < 2; ++kh) {
        bf16x8 wf = *(const bf16x8*)&Bs[((wave << 4) + m16) * LDT + (kh << 5) + koff];
#pragma unroll
        for (int it = 0; it < 4; ++it) {
          bf16x8 af = *(const bf16x8*)&As[((it << 4) + m16) * LDT + (kh << 5) + koff];
          acc[it] = __builtin_amdgcn_mfma_f32_16x16x32_bf16(wf, af, acc[it], 0, 0, 0);
        }
      }
    }
    __builtin_amdgcn_s_setprio(0);
  }

  if (MODE == 0) {
    float* out = (float*)outv;
#pragma unroll
    for (int nt = 0; nt < 4; ++nt) {
      float bn = bias[n0 + (nt << 4) + m16];
#pragma unroll
      for (int r = 0; r < 4; ++r) {
        int i = i0 + (wave << 4) + (quad << 2) + r;
        out[(size_t)i * 512 + n0 + (nt << 4) + m16] = acc[nt][r] + bn;
      }
    }
  } else if (MODE == 2) {
    ushort* out = (ushort*)outv;
    const int b = i0 >> 11, l0 = i0 & 2047, h = n0 >> 6;
#pragma unroll
    for (int nt = 0; nt < 4; ++nt) {
      float bn = bias[n0 + (nt << 4) + m16];
      int d = (nt << 4) + m16;
#pragma unroll
      for (int r = 0; r < 4; ++r) {
        int il = (wave << 4) + (quad << 2) + r;
        out[((size_t)(b * 8 + h) * 2048 + l0 + il) * 64 + d] =
            f2bf((acc[nt][r] + bn) * oscale);
      }
    }
  } else {  // MODE 1: Vt [bh][d][l], masked columns -> 0
    ushort* out = (ushort*)outv;
    const int b = i0 >> 11, l0 = i0 & 2047, h = n0 >> 6;
    float4 b4 = *(const float4*)(bias + n0 + (wave << 4) + (quad << 2));
    float bb[4] = {b4.x, b4.y, b4.z, b4.w};
    float mkf[4];
#pragma unroll
    for (int it = 0; it < 4; ++it)
      mkf[it] = (mvec[b * 2048 + l0 + (it << 4) + m16] != 0) ? 1.f : 0.f;
#pragma unroll
    for (int r = 0; r < 4; ++r) {
      int d = (wave << 4) + (quad << 2) + r;
#pragma unroll
      for (int it = 0; it < 4; ++it) {
        out[((size_t)(b * 8 + h) * 64 + d) * 2048 + l0 + (it << 4) + m16] =
            f2bf((acc[it][r] + bb[r]) * mkf[it]);
      }
    }
  }
}

template <int MODE, int AFP32>
__global__ __launch_bounds__(256) void gemm_tile(const void* __restrict__ A,
                                                 const ushort* __restrict__ Wt,
                                                 const float* __restrict__ bias,
                                                 void* __restrict__ outv) {
  gemm_tile_body<MODE, AFP32>(A, Wt, bias, nullptr, outv, blockIdx.x,
                              blockIdx.y, 1.f);
}

// Merged QKV projection with fused fp32->bf16 A staging. Grid (8, 64, 3).
// Q output pre-scaled by 0.125 (exact in bf16); rel pre-scaled by 8 so qrel
// values are bitwise unchanged.
__global__ __launch_bounds__(256) void gemm_qkv(
    const float* __restrict__ q, const float* __restrict__ k,
    const float* __restrict__ v, const ushort* __restrict__ Wt,
    const float* __restrict__ bq, const float* __restrict__ bk,
    const float* __restrict__ bv, const int* __restrict__ mask,
    ushort* __restrict__ Qw, ushort* __restrict__ Kw, ushort* __restrict__ Vtw) {
  const int z = blockIdx.z;
  if (z == 0) {
    gemm_tile_body<2, 1>(q, Wt, bq, nullptr, (void*)Qw, blockIdx.x, blockIdx.y,
                         0.125f);
  } else if (z == 1) {
    gemm_tile_body<2, 1>(k, Wt + 262144, bk, nullptr, (void*)Kw, blockIdx.x,
                         blockIdx.y, 1.f);
  } else {
    gemm_tile_body<1, 1>(v, Wt + 2 * 262144, bv, mask, (void*)Vtw, blockIdx.x,
                         blockIdx.y, 1.f);
  }
}

// ============================================================================
// qrel_tile: qrelh[bh][i][r] (fp16) = sum_d Q[bh][i][d]*rel8[r][d]. LDS-tiled
// single-K-step GEMM (K=64). Grid (8, 32, 16). fp16 out halves the 65 MB
// intermediate (bias |values| ~ 25 << fp16 range; +2^-11 rel rounding).
// ============================================================================
__global__ __launch_bounds__(256) void qrel_tile(const ushort* __restrict__ Qw,
                                                 const ushort* __restrict__ rel8,
                                                 ushort* __restrict__ qrelh) {
  __shared__ ushort As[64 * LDT];
  __shared__ ushort Bs[64 * LDT];
  const int t = threadIdx.x;
  const int lane = t & 63, wave = t >> 6;
  const int m16 = lane & 15, quad = lane >> 4;
  const int koff = quad << 3;
  const int r0 = blockIdx.x * 64;
  const int i0 = blockIdx.y * 64;
  const int bh = blockIdx.z;
  const int row0 = t >> 3, off0 = (t & 7) << 3;
  const int row1 = (t + 256) >> 3, off1 = ((t + 256) & 7) << 3;

  *(uint4*)&As[row0 * LDT + off0] =
      *(const uint4*)(Qw + ((size_t)bh * 2048 + i0 + row0) * 64 + off0);
  *(uint4*)&As[row1 * LDT + off1] =
      *(const uint4*)(Qw + ((size_t)bh * 2048 + i0 + row1) * 64 + off1);
  *(uint4*)&Bs[row0 * LDT + off0] =
      *(const uint4*)(rel8 + (size_t)(r0 + row0) * 64 + off0);
  *(uint4*)&Bs[row1 * LDT + off1] =
      *(const uint4*)(rel8 + (size_t)(r0 + row1) * 64 + off1);
  __syncthreads();

  f32x4 acc[4] = {{0.f, 0.f, 0.f, 0.f}, {0.f, 0.f, 0.f, 0.f},
                  {0.f, 0.f, 0.f, 0.f}, {0.f, 0.f, 0.f, 0.f}};
#pragma unroll
  for (int kh = 0; kh < 2; ++kh) {
    bf16x8 af = *(const bf16x8*)&As[((wave << 4) + m16) * LDT + (kh << 5) + koff];
#pragma unroll
    for (int nt = 0; nt < 4; ++nt) {
      bf16x8 wf = *(const bf16x8*)&Bs[((nt << 4) + m16) * LDT + (kh << 5) + koff];
      acc[nt] = __builtin_amdgcn_mfma_f32_16x16x32_bf16(af, wf, acc[nt], 0, 0, 0);
    }
  }

#pragma unroll
  for (int nt = 0; nt < 4; ++nt) {
    int r = r0 + (nt << 4) + m16;
    if (r < NREL_PAD) {
#pragma unroll
      for (int rg = 0; rg < 4; ++rg) {
        int i = i0 + (wave << 4) + (quad << 2) + rg;
        qrelh[((size_t)bh * 2048 + i) * NREL_PAD + r] = f2h(acc[nt][rg]);
      }
    }
  }
}

// ============================================================================
// qrel gather (fp16 table) for one 64-j tile; wave-uniform clamp shortcut
// with hoisted edge values (zero loads on fully-clamped tiles).
// ============================================================================
__device__ __forceinline__ void gather_qv(float qv[4][4],
                                          const ushort* __restrict__ qrow,
                                          float e_lo, float e_hi,
                                          int iq, int iw0, int j0, int quad) {
  if (j0 - iw0 >= 264) {
#pragma unroll
    for (int jt = 0; jt < 4; ++jt)
#pragma unroll
      for (int r = 0; r < 4; ++r) qv[jt][r] = e_hi;
  } else if (iw0 - j0 >= 312) {
#pragma unroll
    for (int jt = 0; jt < 4; ++jt)
#pragma unroll
      for (int r = 0; r < 4; ++r) qv[jt][r] = e_lo;
  } else {
#pragma unroll
    for (int jt = 0; jt < 4; ++jt) {
#pragma unroll
      for (int r = 0; r < 4; ++r) {
        int j = j0 + (jt << 4) + (quad << 2) + r;
        int rr = min(NREL - 1, max(0, j - iq + 249));
        qv[jt][r] = h2f(qrow[rr]);
      }
    }
  }
}

// ============================================================================
// Flash attention (R6/R9 structure): LDS-staged K/V, register prefetch,
// swapped-operand QK^T with bias-initialized C, in-register softmax,
// defer-max, MFMA l-accumulation, XCD-aware block swizzle. Main loop unrolled
// 2x with explicit A/B register sets (no rotate movs; same peak liveness).
// ============================================================================
__global__ __launch_bounds__(256) void flash_attn(
    const ushort* __restrict__ Qw, const ushort* __restrict__ Kw,
    const ushort* __restrict__ Vt, const ushort* __restrict__ qrelh,
    const ushort* __restrict__ maskbf, ushort* __restrict__ attnbf) {
  __shared__ ushort QPs[64 * LDB];  // Q tile [i][d]; later P [i][j]
  __shared__ ushort Ks[64 * LDB];   // [j][d]
  __shared__ ushort Vs[64 * LDB];   // [d][j]
  const int t = threadIdx.x;
  const int lane = t & 63, wave = t >> 6;
  const int m16 = lane & 15, quad = lane >> 4;
  const int koff = quad << 3;
  const int bid = ((int)blockIdx.y << 5) + (int)blockIdx.x;
  const int swz = ((bid & 7) << 6) + (bid >> 3);  // XCD-contiguous chunks
  const int i0 = (swz & 31) << 6;
  const int bh = swz >> 5;
  const int b = bh >> 3, h = bh & 7;
  const ushort* Qb = Qw + (size_t)bh * 2048 * 64;
  const ushort* Kb = Kw + (size_t)bh * 2048 * 64;
  const ushort* Vb = Vt + (size_t)bh * 64 * 2048;
  const ushort* mbf = maskbf + b * 2048;
  const int iw0 = i0 + (wave << 4);
  const int iq = iw0 + m16;  // this lane's output row
  const ushort* qrow = qrelh + ((size_t)bh * 2048 + iq) * NREL_PAD;
  const float e_lo = h2f(qrow[0]), e_hi = h2f(qrow[NREL - 1]);

  const int row0 = t >> 3, off0 = (t & 7) << 3;
  const int row1 = (t + 256) >> 3, off1 = ((t + 256) & 7) << 3;

  // Q tile -> LDS
  *(uint4*)&QPs[row0 * LDB + off0] =
      *(const uint4*)(Qb + (size_t)(i0 + row0) * 64 + off0);
  *(uint4*)&QPs[row1 * LDB + off1] =
      *(const uint4*)(Qb + (size_t)(i0 + row1) * 64 + off1);
  __syncthreads();

  bf16x8 qa0 = *(const bf16x8*)&QPs[((wave << 4) + m16) * LDB + koff];
  bf16x8 qa1 = *(const bf16x8*)&QPs[((wave << 4) + m16) * LDB + 32 + koff];

  float m_i = -INFINITY;
  f32x4 oacc[4];
  f32x4 lacc = {0.f, 0.f, 0.f, 0.f};
#pragma unroll
  for (int dt = 0; dt < 4; ++dt) oacc[dt] = (f32x4){0.f, 0.f, 0.f, 0.f};

  // ---- prologue prefetch (set A) for j0 = 0 ----
  uint4 krA0 = *(const uint4*)(Kb + (size_t)row0 * 64 + off0);
  uint4 krA1 = *(const uint4*)(Kb + (size_t)row1 * 64 + off1);
  uint4 vrA0 = *(const uint4*)(Vb + (size_t)row0 * 2048 + off0);
  uint4 vrA1 = *(const uint4*)(Vb + (size_t)row1 * 2048 + off1);
  bf16x8 mfA0 = *(const bf16x8*)(mbf + koff);
  bf16x8 mfA1 = *(const bf16x8*)(mbf + 32 + koff);
  float qvA[4][4];
  gather_qv(qvA, qrow, e_lo, e_hi, iq, iw0, 0, quad);
  uint4 krB0, krB1, vrB0, vrB1;
  bf16x8 mfB0, mfB1;
  float qvB[4][4];

#define FLASH_STEP(KR0, KR1, VR0, VR1, MF0, MF1, QV,                          \
                   KN0, KN1, VN0, VN1, MG0, MG1, QN, JN)                      \
  do {                                                                        \
    __syncthreads();                                                          \
    *(uint4*)&Ks[row0 * LDB + off0] = KR0;                                    \
    *(uint4*)&Ks[row1 * LDB + off1] = KR1;                                    \
    *(uint4*)&Vs[row0 * LDB + off0] = VR0;                                    \
    *(uint4*)&Vs[row1 * LDB + off1] = VR1;                                    \
    __syncthreads();                                                          \
    KN0 = *(const uint4*)(Kb + (size_t)((JN) + row0) * 64 + off0);            \
    KN1 = *(const uint4*)(Kb + (size_t)((JN) + row1) * 64 + off1);            \
    VN0 = *(const uint4*)(Vb + (size_t)row0 * 2048 + (JN) + off0);            \
    VN1 = *(const uint4*)(Vb + (size_t)row1 * 2048 + (JN) + off1);            \
    MG0 = *(const bf16x8*)(mbf + (JN) + koff);                                \
    MG1 = *(const bf16x8*)(mbf + (JN) + 32 + koff);                           \
    gather_qv(QN, qrow, e_lo, e_hi, iq, iw0, (JN), quad);                     \
    f32x4 sacc[4];                                                            \
    __builtin_amdgcn_s_setprio(1);                                            \
    _Pragma("unroll")                                                         \
    for (int jt = 0; jt < 4; ++jt) {                                          \
      bf16x8 kf0 = *(const bf16x8*)&Ks[((jt << 4) + m16) * LDB + koff];       \
      bf16x8 kf1 = *(const bf16x8*)&Ks[((jt << 4) + m16) * LDB + 32 + koff];  \
      f32x4 z = {QV[jt][0], QV[jt][1], QV[jt][2], QV[jt][3]};                 \
      z = __builtin_amdgcn_mfma_f32_16x16x32_bf16(kf0, qa0, z, 0, 0, 0);      \
      z = __builtin_amdgcn_mfma_f32_16x16x32_bf16(kf1, qa1, z, 0, 0, 0);      \
      sacc[jt] = z;                                                           \
    }                                                                         \
    __builtin_amdgcn_s_setprio(0);                                            \
    float t0 = fmaxf(fmaxf(sacc[0][0], sacc[0][1]),                           \
                     fmaxf(sacc[0][2], sacc[0][3]));                          \
    float t1 = fmaxf(fmaxf(sacc[1][0], sacc[1][1]),                           \
                     fmaxf(sacc[1][2], sacc[1][3]));                          \
    float t2 = fmaxf(fmaxf(sacc[2][0], sacc[2][1]),                           \
                     fmaxf(sacc[2][2], sacc[2][3]));                          \
    float t3 = fmaxf(fmaxf(sacc[3][0], sacc[3][1]),                           \
                     fmaxf(sacc[3][2], sacc[3][3]));                          \
    float mx = fmaxf(fmaxf(t0, t1), fmaxf(t2, t3));                           \
    mx = fmaxf(mx, __shfl_xor(mx, 16));                                       \
    mx = fmaxf(mx, __shfl_xor(mx, 32));                                       \
    if (__any(mx > m_i + 8.f)) {                                              \
      float mnew = fmaxf(m_i, mx);                                            \
      float al = __expf(m_i - mnew);                                          \
      m_i = mnew;                                                             \
      _Pragma("unroll")                                                       \
      for (int dt = 0; dt < 4; ++dt) {                                        \
        oacc[dt][0] *= al; oacc[dt][1] *= al;                                 \
        oacc[dt][2] *= al; oacc[dt][3] *= al;                                 \
      }                                                                       \
      lacc[0] *= al; lacc[1] *= al; lacc[2] *= al; lacc[3] *= al;             \
    }                                                                         \
    const int prow = ((wave << 4) + m16) * LDB;                               \
    _Pragma("unroll")                                                         \
    for (int jt = 0; jt < 4; ++jt) {                                          \
      ushort4 pk;                                                             \
      pk.x = f2bf(__expf(sacc[jt][0] - m_i));                                 \
      pk.y = f2bf(__expf(sacc[jt][1] - m_i));                                 \
      pk.z = f2bf(__expf(sacc[jt][2] - m_i));                                 \
      pk.w = f2bf(__expf(sacc[jt][3] - m_i));                                 \
      *(ushort4*)&QPs[prow + (jt << 4) + (quad << 2)] = pk;                   \
    }                                                                         \
    __asm__ volatile("s_waitcnt lgkmcnt(0)" ::: "memory");                    \
    bf16x8 pa0 = *(const bf16x8*)&QPs[prow + koff];                           \
    bf16x8 pa1 = *(const bf16x8*)&QPs[prow + 32 + koff];                      \
    __builtin_amdgcn_s_setprio(1);                                            \
    lacc = __builtin_amdgcn_mfma_f32_16x16x32_bf16(MF0, pa0, lacc, 0, 0, 0);  \
    lacc = __builtin_amdgcn_mfma_f32_16x16x32_bf16(MF1, pa1, lacc, 0, 0, 0);  \
    _Pragma("unroll")                                                         \
    for (int dt = 0; dt < 4; ++dt) {                                          \
      bf16x8 vf0 = *(const bf16x8*)&Vs[((dt << 4) + m16) * LDB + koff];       \
      bf16x8 vf1 = *(const bf16x8*)&Vs[((dt << 4) + m16) * LDB + 32 + koff];  \
      oacc[dt] =                                                              \
          __builtin_amdgcn_mfma_f32_16x16x32_bf16(vf0, pa0, oacc[dt], 0, 0, 0); \
      oacc[dt] =                                                              \
          __builtin_amdgcn_mfma_f32_16x16x32_bf16(vf1, pa1, oacc[dt], 0, 0, 0); \
    }                                                                         \
    __builtin_amdgcn_s_setprio(0);                                            \
  } while (0)

  for (int j0 = 0; j0 < 2048; j0 += 128) {
    FLASH_STEP(krA0, krA1, vrA0, vrA1, mfA0, mfA1, qvA,
               krB0, krB1, vrB0, vrB1, mfB0, mfB1, qvB, j0 + 64);
    FLASH_STEP(krB0, krB1, vrB0, vrB1, mfB0, mfB1, qvB,
               krA0, krA1, vrA0, vrA1, mfA0, mfA1, qvA, (j0 + 128) & 2047);
  }
#undef FLASH_STEP

  // epilogue: lane holds O[iq][d = dt*16 + quad*4 + r]; l = lacc[0]
  float inv = 1.0f / lacc[0];
  ushort* dst = attnbf + (size_t)(b * 2048 + iq) * 512 + h * 64;
#pragma unroll
  for (int dt = 0; dt < 4; ++dt) {
    ushort4 st;
    st.x = f2bf(oacc[dt][0] * inv);
    st.y = f2bf(oacc[dt][1] * inv);
    st.z = f2bf(oacc[dt][2] * inv);
    st.w = f2bf(oacc[dt][3] * inv);
    *(ushort4*)(dst + (dt << 4) + (quad << 2)) = st;
  }
}

// ============================================================================
extern "C" void kernel_launch(void* const* d_in, const int* in_sizes, int n_in,
                              void* d_out, int out_size, void* d_ws,
                              size_t ws_size, hipStream_t stream) {
  const float* query = (const float*)d_in[0];
  const float* key   = (const float*)d_in[1];
  const float* value = (const float*)d_in[2];
  const int*   mask  = (const int*)d_in[3];
  const float* Wq = (const float*)d_in[4];
  const float* bq = (const float*)d_in[5];
  const float* Wk = (const float*)d_in[6];
  const float* bk = (const float*)d_in[7];
  const float* Wv = (const float*)d_in[8];
  const float* bv = (const float*)d_in[9];
  const float* Wo = (const float*)d_in[10];
  const float* bo = (const float*)d_in[11];
  const float* rel = (const float*)d_in[12];

  char* w = (char*)d_ws;
  size_t off = 0;
  ushort* Qw  = (ushort*)(w + off); off += (size_t)16 * 2048 * 64 * 2;       // 4 MB
  ushort* Kw  = (ushort*)(w + off); off += (size_t)16 * 2048 * 64 * 2;       // 4 MB
  ushort* Vtw = (ushort*)(w + off); off += (size_t)16 * 64 * 2048 * 2;       // 4 MB
  ushort* Wt  = (ushort*)(w + off); off += (size_t)4 * 512 * 512 * 2;        // 2 MB
  ushort* qrelh = (ushort*)(w + off); off += (size_t)16 * 2048 * NREL_PAD * 2; // 32.8 MB
  ushort* attnbf = (ushort*)(w + off); off += (size_t)4096 * 512 * 2;        // 4 MB
  ushort* maskbf = (ushort*)(w + off); off += (size_t)2 * 2048 * 2;          // 8 KB
  ushort* rel8 = (ushort*)(w + off); off += (size_t)512 * 64 * 2;            // 64 KB
  float* out = (float*)d_out;

  dim3 bb(256);
  hipLaunchKernelGGL(prep_wt, dim3(8, 8, 4), bb, 0, stream, Wq, Wk, Wv, Wo,
                     mask, rel, Wt, maskbf, rel8);
  hipLaunchKernelGGL(gemm_qkv, dim3(8, 64, 3), bb, 0, stream, query, key, value,
                     Wt, bq, bk, bv, mask, Qw, Kw, Vtw);
  hipLaunchKernelGGL(qrel_tile, dim3(8, 32, 16), bb, 0, stream, Qw, rel8, qrelh);
  hipLaunchKernelGGL(flash_attn, dim3(32, 16), bb, 0, stream, Qw, Kw, Vtw,
                     qrelh, maskbf, attnbf);
  hipLaunchKernelGGL((gemm_tile<0, 0>), dim3(8, 64), bb, 0, stream, attnbf,
                     Wt + 3 * 262144, bo, (void*)out);
}